// Round 13
// baseline (314.642 us; speedup 1.0000x reference)
//
#include <hip/hip_runtime.h>
#include <hip/hip_bf16.h>
#include <cstdint>

#define NN 40000
#define NE 100000
#define NEP 100096           // 32-aligned edge count
#define NB 1024
#define MAXN 192             // per-graph LDS node cache capacity

typedef _Float16 halfT;
typedef _Float16 half8 __attribute__((ext_vector_type(8)));
typedef float f32x4 __attribute__((ext_vector_type(4)));

static __device__ __forceinline__ float sigf(float x){ return 1.f/(1.f + __expf(-x)); }
static __device__ __forceinline__ float tanh_f(float x){ float e = __expf(2.f * x); return 1.f - 2.f/(e + 1.f); }

// =====================================================================
// k_setup: one kernel, 6 block-ranges (all vectorized)  [unchanged from R12]
// =====================================================================
__global__ __launch_bounds__(256) void k_setup(
    const float* __restrict__ x, const float* __restrict__ lin0_W, const float* __restrict__ lin0_b,
    const float* __restrict__ ea, const float* __restrict__ W1, const float* __restrict__ b1,
    const float* __restrict__ W2, const float* __restrict__ b2,
    const int* __restrict__ dstA, const int* __restrict__ batch,
    const float* __restrict__ gWih, const float* __restrict__ gWhh,
    const float* __restrict__ lWih, const float* __restrict__ lWhh, const float* __restrict__ lin1_W,
    float* __restrict__ h, halfT* __restrict__ hH, halfT* __restrict__ ehF, halfT* __restrict__ BfF,
    float* __restrict__ deg, float* __restrict__ WgT, float* __restrict__ WhT,
    float* __restrict__ lWihT, float* __restrict__ lWhhT, float* __restrict__ lin1T,
    int* __restrict__ starts)
{
    int b = blockIdx.x, tid = threadIdx.x;
    if (b < 1250){
        __shared__ float sW[32 * 30];
        __shared__ float sB[32];
        for (int idx = tid; idx < 960; idx += 256) sW[idx] = lin0_W[idx];
        if (tid < 32) sB[tid] = lin0_b[tid];
        __syncthreads();
        int t8 = b * 256 + tid;             // [0, NN*8)
        int i = t8 >> 3, q4 = t8 & 7;       // node, channel-quad
        const float* xr = x + (size_t)i * 30;
        float xv[30];
        #pragma unroll
        for (int f = 0; f < 30; f++) xv[f] = xr[f];
        float r[4];
        #pragma unroll
        for (int cc = 0; cc < 4; cc++){
            int c = q4 * 4 + cc;
            const float* wr = &sW[c * 30];
            float s = sB[c];
            #pragma unroll
            for (int f = 0; f < 30; f++) s += xv[f] * wr[f];
            r[cc] = fmaxf(s, 0.f);
        }
        *(float4*)(h + (size_t)i * 32 + q4 * 4) = *(float4*)r;
        halfT rh[4];
        #pragma unroll
        for (int cc = 0; cc < 4; cc++) rh[cc] = (halfT)r[cc];
        *(uint2*)(hH + (size_t)i * 32 + q4 * 4) = *(uint2*)rh;
    } else if (b < 7506){
        __shared__ float sW1[128 * 11];
        __shared__ float sb1[128];
        for (int idx = tid; idx < 1408; idx += 256) sW1[idx] = W1[idx];
        if (tid < 128) sb1[tid] = b1[tid];
        __syncthreads();
        int t8 = (b - 1250) * 256 + tid;    // [0, NEP*16)
        int ch = t8 & 63;
        int s4 = (t8 >> 6) & 3;
        int g16 = t8 >> 8;
        int m = ch & 15, q = ch >> 4;       // lane-linear content
        int e = g16 * 16 + m;
        int kb = 32 * s4 + q * 8;
        halfT v[8];
        if (e < NE){
            const float* xr = ea + (size_t)e * 11;
            float xv[11];
            #pragma unroll
            for (int f = 0; f < 11; f++) xv[f] = xr[f];
            #pragma unroll
            for (int i8 = 0; i8 < 8; i8++){
                int k = kb + i8;
                const float* wr = &sW1[k * 11];
                float s = sb1[k];
                #pragma unroll
                for (int f = 0; f < 11; f++) s += xv[f] * wr[f];
                v[i8] = (halfT)fmaxf(s, 0.f);
            }
        } else {
            #pragma unroll
            for (int i8 = 0; i8 < 8; i8++) v[i8] = (halfT)0.f;
        }
        *(half8*)(ehF + (size_t)t8 * 8) = *(half8*)v;
    } else if (b < 8022){
        int gid = (b - 7506) * 256 + tid;   // 129*2*64*8 = 132096
        int i8 = gid & 7;
        int ch = (gid >> 3) & 63;
        int nt = (gid >> 9) & 1;
        int ks = gid >> 10;
        int m = ch & 15, q = ch >> 4;       // lane-linear content
        int o = nt * 16 + m;
        float v;
        if (ks < 128){
            int c = ks >> 2;
            int k = 32 * (ks & 3) + q * 8 + i8;
            v = W2[(size_t)(c * 32 + o) * 128 + k];
        } else {
            int c = q * 8 + i8;
            v = b2[c * 32 + o];
        }
        BfF[gid] = (halfT)v;
    } else if (b < 8413){
        int e = (b - 8022) * 256 + tid;
        if (e < NE) atomicAdd(&deg[dstA[e]], 1.f);
    } else if (b < 8493){
        int t = (b - 8413) * 256 + tid;     // 20480
        if (t < 3072){ int k = t / 96, j = t % 96; WgT[t] = gWih[(size_t)j * 32 + k]; }
        else if (t < 6144){ int t2 = t - 3072; int k = t2 / 96, j = t2 % 96; WhT[t2] = gWhh[(size_t)j * 32 + k]; }
        else if (t < 14336){ int t2 = t - 6144; int k = t2 >> 7, j = t2 & 127; lWihT[t2] = lWih[(size_t)j * 64 + k]; }
        else if (t < 18432){ int t2 = t - 14336; int k = t2 >> 7, j = t2 & 127; lWhhT[t2] = lWhh[(size_t)j * 32 + k]; }
        else { int t2 = t - 18432; int k = t2 >> 5, c = t2 & 31; lin1T[t2] = lin1_W[(size_t)c * 64 + k]; }
    } else {
        int g = (b - 8493) * 256 + tid;
        if (g > NB) return;
        int lo = 0, hi = NN;
        while (lo < hi){
            int mid = (lo + hi) >> 1;
            if (batch[mid] < g) lo = mid + 1; else hi = mid;
        }
        starts[g] = lo;
    }
}

// =====================================================================
// k_msg4: 512-thread blocks, 8 waves share one LDS B staging.  [unchanged]
// =====================================================================
__global__ __launch_bounds__(512, 4) void k_msg4(
    const halfT* __restrict__ ehF, const halfT* __restrict__ BfF,
    const halfT* __restrict__ hH,
    const int* __restrict__ src, const int* __restrict__ dst,
    float* __restrict__ aggr)
{
    __shared__ halfT sB[2][8192];        // 2 x 16KB
    int tid = threadIdx.x;               // 0..511
    int l = tid & 63;
    int wid = blockIdx.x * 8 + (tid >> 6);
    int m = l & 15, q = l >> 4;
    int eb = wid * 32;
    half8 pre[2];
    #pragma unroll
    for (int p = 0; p < 2; p++)
        pre[p] = *(const half8*)(BfF + (size_t)(p * 512 + tid) * 8);
    #pragma unroll
    for (int p = 0; p < 2; p++)
        *(half8*)(&sB[0][(p * 512 + tid) * 8]) = pre[p];
    half8 u0[4], u1[4], ub0, ub1;
    {
        int e0 = eb + m;      int se0 = (e0 < NE) ? src[e0] : 0;
        int e1 = eb + 16 + m; int se1 = (e1 < NE) ? src[e1] : 0;
        const halfT* p0 = hH + (size_t)se0 * 32;
        const halfT* p1 = hH + (size_t)se1 * 32;
        #pragma unroll
        for (int j = 0; j < 4; j++){
            u0[j] = *(const half8*)(p0 + j * 8);
            u1[j] = *(const half8*)(p1 + j * 8);
        }
        ub0 = *(const half8*)(p0 + q * 8);
        ub1 = *(const half8*)(p1 + q * 8);
    }
    half8 eh0[4], eh1[4];
    {
        int g0 = eb >> 4;
        #pragma unroll
        for (int s = 0; s < 4; s++){
            eh0[s] = *(const half8*)(ehF + ((size_t)(g0 * 4 + s) * 64 + l) * 8);
            eh1[s] = *(const half8*)(ehF + ((size_t)((g0 + 1) * 4 + s) * 64 + l) * 8);
        }
    }
    __syncthreads();
    #pragma unroll
    for (int p = 0; p < 2; p++)
        pre[p] = *(const half8*)(BfF + (size_t)8192 + (size_t)(p * 512 + tid) * 8);
    f32x4 acc00 = {0,0,0,0}, acc01 = {0,0,0,0}, acc10 = {0,0,0,0}, acc11 = {0,0,0,0};
    #pragma unroll
    for (int g = 0; g < 16; g++){
        const int cur = g & 1;
        #pragma unroll
        for (int j = 0; j < 8; j++){
            const int ks = g * 8 + j;
            half8 b0 = *(const half8*)(&sB[cur][(j * 2 + 0) * 512 + l * 8]);
            half8 b1 = *(const half8*)(&sB[cur][(j * 2 + 1) * 512 + l * 8]);
            const int c = ks >> 2, s = ks & 3;
            halfT uc0 = u0[c >> 3][c & 7];
            halfT uc1 = u1[c >> 3][c & 7];
            half8 a0 = eh0[s] * uc0;
            half8 a1 = eh1[s] * uc1;
            acc00 = __builtin_amdgcn_mfma_f32_16x16x32_f16(a0, b0, acc00, 0, 0, 0);
            acc01 = __builtin_amdgcn_mfma_f32_16x16x32_f16(a0, b1, acc01, 0, 0, 0);
            acc10 = __builtin_amdgcn_mfma_f32_16x16x32_f16(a1, b0, acc10, 0, 0, 0);
            acc11 = __builtin_amdgcn_mfma_f32_16x16x32_f16(a1, b1, acc11, 0, 0, 0);
        }
        if (g + 1 < 16){
            #pragma unroll
            for (int p = 0; p < 2; p++)
                *(half8*)(&sB[cur ^ 1][(p * 512 + tid) * 8]) = pre[p];
            if (g + 2 < 16){
                #pragma unroll
                for (int p = 0; p < 2; p++)
                    pre[p] = *(const half8*)(BfF + (size_t)(g + 2) * 8192 + (size_t)(p * 512 + tid) * 8);
            }
        }
        __syncthreads();
    }
    {
        half8 b0 = *(const half8*)(BfF + (size_t)256 * 512 + l * 8);
        half8 b1 = *(const half8*)(BfF + (size_t)257 * 512 + l * 8);
        acc00 = __builtin_amdgcn_mfma_f32_16x16x32_f16(ub0, b0, acc00, 0, 0, 0);
        acc01 = __builtin_amdgcn_mfma_f32_16x16x32_f16(ub0, b1, acc01, 0, 0, 0);
        acc10 = __builtin_amdgcn_mfma_f32_16x16x32_f16(ub1, b0, acc10, 0, 0, 0);
        acc11 = __builtin_amdgcn_mfma_f32_16x16x32_f16(ub1, b1, acc11, 0, 0, 0);
    }
    #pragma unroll
    for (int r = 0; r < 4; r++){
        int ea0 = eb + q * 4 + r;
        if (ea0 < NE){
            int d = dst[ea0];
            atomicAdd(&aggr[(size_t)d * 32 + m],      acc00[r]);
            atomicAdd(&aggr[(size_t)d * 32 + 16 + m], acc01[r]);
        }
        int ea1 = eb + 16 + q * 4 + r;
        if (ea1 < NE){
            int d = dst[ea1];
            atomicAdd(&aggr[(size_t)d * 32 + m],      acc10[r]);
            atomicAdd(&aggr[(size_t)d * 32 + 16 + m], acc11[r]);
        }
    }
}

// =====================================================================
// k_gru R13: weights staged in LDS (conflict-free lane-stride-4B reads),
// 64 nodes per block (8 passes x 8 nodes), fast transcendentals.
// Consumes aggr and re-zeroes it. Writes h + hH.
// =====================================================================
__global__ __launch_bounds__(256) void k_gru(
    float* __restrict__ aggr, const float* __restrict__ deg, float* __restrict__ h,
    halfT* __restrict__ hH,
    const float* __restrict__ rootW, const float* __restrict__ cb,
    const float* __restrict__ WgT, const float* __restrict__ WhT,
    const float* __restrict__ gbih, const float* __restrict__ gbhh)
{
    __shared__ float sR[1024];          // rootW [k*32+c]
    __shared__ float sG[3072];          // WgT   [k*96+j]
    __shared__ float sHW[3072];         // WhT   [k*96+j]
    __shared__ float sb[224];           // gbih(96) gbhh(96) cb(32)
    int tid = threadIdx.x;
    for (int i2 = tid; i2 < 1024; i2 += 256) sR[i2] = rootW[i2];
    for (int i2 = tid; i2 < 3072; i2 += 256){ sG[i2] = WgT[i2]; sHW[i2] = WhT[i2]; }
    if (tid < 96){ sb[tid] = gbih[tid]; sb[96 + tid] = gbhh[tid]; }
    if (tid < 32) sb[192 + tid] = cb[tid];
    __syncthreads();
    int c = tid & 31;
    #pragma unroll 1
    for (int p = 0; p < 8; p++){
        int i = blockIdx.x * 64 + p * 8 + (tid >> 5);
        size_t base = (size_t)i * 32 + c;
        float hq = h[base];
        float av = aggr[base];
        aggr[base] = 0.f;
        float invd = 1.f / fmaxf(deg[i], 1.f);
        float mv = av * invd + sb[192 + c];
        #pragma unroll 8
        for (int k = 0; k < 32; k++)
            mv += __shfl(hq, k, 32) * sR[k * 32 + c];
        mv = fmaxf(mv, 0.f);
        float gr = sb[c],      hr = sb[96 + c];
        float gz = sb[32 + c], hz = sb[128 + c];
        float gn = sb[64 + c], hn = sb[160 + c];
        #pragma unroll 4
        for (int k = 0; k < 32; k++){
            float mk = __shfl(mv, k, 32);
            float hk = __shfl(hq, k, 32);
            const float* wg = &sG[k * 96];
            const float* wh = &sHW[k * 96];
            gr += mk * wg[c];      hr += hk * wh[c];
            gz += mk * wg[32 + c]; hz += hk * wh[32 + c];
            gn += mk * wg[64 + c]; hn += hk * wh[64 + c];
        }
        float r = sigf(gr + hr);
        float z = sigf(gz + hz);
        float n = tanh_f(gn + r * hn);
        float hnew = (1.f - z) * n + z * hq;
        h[base] = hnew;
        hH[base] = (halfT)hnew;
    }
}

// =====================================================================
// k_s2s: LDS-cached Set2Set + final MLP.  [unchanged from R12]
// =====================================================================
__global__ __launch_bounds__(64) void k_s2s(
    const float* __restrict__ h, const int* __restrict__ starts,
    const float* __restrict__ lWihT, const float* __restrict__ lWhhT,
    const float* __restrict__ lbih, const float* __restrict__ lbhh,
    const float* __restrict__ lin1T, const float* __restrict__ lin1_b,
    const float* __restrict__ lin2W, const float* __restrict__ lin2b,
    float* __restrict__ e_buf, float* __restrict__ out)
{
    __shared__ float hl[MAXN * 33];
    __shared__ float al[MAXN];
    __shared__ float hsl[32];
    int g = blockIdx.x, l = threadIdx.x;
    int s0 = starts[g], s1 = starts[g + 1];
    int n = s1 - s0;
    int c = l & 31, grp = l >> 5;
    int nl = (n < MAXN) ? n : MAXN;
    for (int idx = l; idx < nl * 32; idx += 64)
        hl[(idx >> 5) * 33 + (idx & 31)] = h[(size_t)s0 * 32 + idx];
    __syncthreads();
    float qs = 0.f, hsv = 0.f, csv = 0.f;
    for (int t = 0; t < 3; t++){
        float a1 = lbih[l] + lbhh[l];
        float a2 = lbih[l + 64] + lbhh[l + 64];
        #pragma unroll 8
        for (int k = 0; k < 64; k++){
            float qk = __shfl(qs, k);
            a1 += qk * lWihT[k * 128 + l];
            a2 += qk * lWihT[k * 128 + 64 + l];
        }
        #pragma unroll 8
        for (int k = 0; k < 32; k++){
            float hk = __shfl(qs, k);
            a1 += hk * lWhhT[k * 128 + l];
            a2 += hk * lWhhT[k * 128 + 64 + l];
        }
        float gate1 = sigf(a1);
        float gate2 = (l < 32) ? tanhf(a2) : sigf(a2);
        float fv = __shfl(gate1, c + 32);
        float ov = __shfl(gate2, c + 32);
        if (l < 32){
            csv = fv * csv + gate1 * gate2;
            hsv = ov * tanhf(csv);
            hsl[l] = hsv;
        }
        __syncthreads();
        float lmax = -3.4e38f;
        for (int i = l; i < n; i += 64){
            const float* hr = (i < MAXN) ? &hl[i * 33] : &h[(size_t)(s0 + i) * 32];
            float p = 0.f;
            #pragma unroll
            for (int c2 = 0; c2 < 32; c2++) p += hr[c2] * hsl[c2];
            if (i < MAXN) al[i] = p; else e_buf[s0 + i] = p;
            lmax = fmaxf(lmax, p);
        }
        #pragma unroll
        for (int o = 1; o < 64; o <<= 1) lmax = fmaxf(lmax, __shfl_xor(lmax, o));
        float lsum = 0.f;
        for (int i = l; i < n; i += 64){
            float e = (i < MAXN) ? al[i] : e_buf[s0 + i];
            float a = expf(e - lmax);
            if (i < MAXN) al[i] = a; else e_buf[s0 + i] = a;
            lsum += a;
        }
        #pragma unroll
        for (int o = 1; o < 64; o <<= 1) lsum += __shfl_xor(lsum, o);
        float inv = (lsum > 0.f) ? 1.f / lsum : 0.f;
        __syncthreads();
        float acc = 0.f;
        for (int i = grp; i < n; i += 2){
            float a = (i < MAXN) ? al[i] : e_buf[s0 + i];
            const float* hr = (i < MAXN) ? &hl[i * 33] : &h[(size_t)(s0 + i) * 32];
            acc += a * hr[c];
        }
        acc *= inv;
        acc += __shfl_xor(acc, 32);
        qs = (l < 32) ? hsv : acc;
        __syncthreads();
    }
    float s = lin1_b[c];
    #pragma unroll 8
    for (int k = 0; k < 64; k++){
        float qk = __shfl(qs, k);
        s += qk * lin1T[k * 32 + c];
    }
    float pp = (l < 32) ? fmaxf(s, 0.f) * lin2W[c] : 0.f;
    pp += __shfl_xor(pp, 1);  pp += __shfl_xor(pp, 2);
    pp += __shfl_xor(pp, 4);  pp += __shfl_xor(pp, 8);
    pp += __shfl_xor(pp, 16); pp += __shfl_xor(pp, 32);
    if (l == 0) out[g] = pp + lin2b[0];
}

extern "C" void kernel_launch(void* const* d_in, const int* in_sizes, int n_in,
                              void* d_out, int out_size, void* d_ws, size_t ws_size,
                              hipStream_t stream){
    (void)in_sizes; (void)n_in; (void)out_size;
    const float* x        = (const float*)d_in[0];
    const float* ea       = (const float*)d_in[1];
    const int*   ei       = (const int*)d_in[2];
    const int*   batch    = (const int*)d_in[3];
    const float* lin0_W   = (const float*)d_in[4];
    const float* lin0_b   = (const float*)d_in[5];
    const float* mlp_W1   = (const float*)d_in[6];
    const float* mlp_b1   = (const float*)d_in[7];
    const float* mlp_W2   = (const float*)d_in[8];
    const float* mlp_b2   = (const float*)d_in[9];
    const float* root_W   = (const float*)d_in[10];
    const float* conv_b   = (const float*)d_in[11];
    const float* gWih     = (const float*)d_in[12];
    const float* gWhh     = (const float*)d_in[13];
    const float* gbih     = (const float*)d_in[14];
    const float* gbhh     = (const float*)d_in[15];
    const float* lWih     = (const float*)d_in[16];
    const float* lWhh     = (const float*)d_in[17];
    const float* lbih     = (const float*)d_in[18];
    const float* lbhh     = (const float*)d_in[19];
    const float* lin1_W   = (const float*)d_in[20];
    const float* lin1_b   = (const float*)d_in[21];
    const float* lin2_W   = (const float*)d_in[22];
    const float* lin2_b   = (const float*)d_in[23];
    const int* src = ei;
    const int* dst = ei + NE;
    float* out = (float*)d_out;

    char* w = (char*)d_ws;
    size_t off = 0;
    auto alloc = [&](size_t bytes) -> void* {
        void* p = w + off;
        off = (off + bytes + 255) & ~(size_t)255;
        return p;
    };
    float* deg    = (float*)alloc((size_t)NN * 4);            // contiguous with aggr
    float* aggr   = (float*)alloc((size_t)NN * 32 * 4);
    float* h      = (float*)alloc((size_t)NN * 32 * 4);
    halfT* hH     = (halfT*)alloc((size_t)NN * 32 * 2);
    halfT* ehF    = (halfT*)alloc((size_t)NEP * 128 * 2);
    halfT* BfF    = (halfT*)alloc((size_t)129 * 2 * 64 * 8 * 2);
    int*   starts = (int*)alloc((size_t)(NB + 1) * 4);
    float* WgT    = (float*)alloc((size_t)3072 * 4);
    float* WhT    = (float*)alloc((size_t)3072 * 4);
    float* lWihT  = (float*)alloc((size_t)8192 * 4);
    float* lWhhT  = (float*)alloc((size_t)4096 * 4);
    float* lin1T  = (float*)alloc((size_t)2048 * 4);
    float* e_buf  = (float*)alloc((size_t)NN * 4);
    if (ws_size < off) return;   // cannot run

    hipMemsetAsync(deg, 0, (size_t)NN * 4 + (size_t)NN * 32 * 4, stream);

    k_setup<<<8498, 256, 0, stream>>>(x, lin0_W, lin0_b, ea, mlp_W1, mlp_b1,
        mlp_W2, mlp_b2, dst, batch, gWih, gWhh, lWih, lWhh, lin1_W,
        h, hH, ehF, BfF, deg, WgT, WhT, lWihT, lWhhT, lin1T, starts);

    for (int t = 0; t < 3; t++){
        k_msg4<<<NEP / 256, 512, 0, stream>>>(ehF, BfF, hH, src, dst, aggr);
        k_gru<<<NN / 64, 256, 0, stream>>>(aggr, deg, h, hH, root_W, conv_b,
                                           WgT, WhT, gbih, gbhh);
    }
    k_s2s<<<NB, 64, 0, stream>>>(h, starts, lWihT, lWhhT, lbih, lbhh,
                                 lin1T, lin1_b, lin2_W, lin2_b, e_buf, out);
}

// Round 15
// 281.921 us; speedup vs baseline: 1.1161x; 1.1161x over previous
//
#include <hip/hip_runtime.h>
#include <hip/hip_bf16.h>
#include <cstdint>

#define NN 40000
#define NE 100000
#define NEP 100096           // 32-aligned edge count
#define NB 1024
#define MAXN 192             // per-graph LDS node cache capacity

typedef _Float16 halfT;
typedef _Float16 half8 __attribute__((ext_vector_type(8)));
typedef float f32x4 __attribute__((ext_vector_type(4)));

static __device__ __forceinline__ float sigf(float x){ return 1.f/(1.f + __expf(-x)); }
static __device__ __forceinline__ float tanh_f(float x){ float e = __expf(2.f * x); return 1.f - 2.f/(e + 1.f); }

// =====================================================================
// k_setup: one kernel, 6 block-ranges (all vectorized)  [unchanged]
// =====================================================================
__global__ __launch_bounds__(256) void k_setup(
    const float* __restrict__ x, const float* __restrict__ lin0_W, const float* __restrict__ lin0_b,
    const float* __restrict__ ea, const float* __restrict__ W1, const float* __restrict__ b1,
    const float* __restrict__ W2, const float* __restrict__ b2,
    const int* __restrict__ dstA, const int* __restrict__ batch,
    const float* __restrict__ gWih, const float* __restrict__ gWhh,
    const float* __restrict__ lWih, const float* __restrict__ lWhh, const float* __restrict__ lin1_W,
    float* __restrict__ h, halfT* __restrict__ hH, halfT* __restrict__ ehF, halfT* __restrict__ BfF,
    float* __restrict__ deg, float* __restrict__ WgT, float* __restrict__ WhT,
    float* __restrict__ lWihT, float* __restrict__ lWhhT, float* __restrict__ lin1T,
    int* __restrict__ starts)
{
    int b = blockIdx.x, tid = threadIdx.x;
    if (b < 1250){
        __shared__ float sW[32 * 30];
        __shared__ float sB[32];
        for (int idx = tid; idx < 960; idx += 256) sW[idx] = lin0_W[idx];
        if (tid < 32) sB[tid] = lin0_b[tid];
        __syncthreads();
        int t8 = b * 256 + tid;             // [0, NN*8)
        int i = t8 >> 3, q4 = t8 & 7;       // node, channel-quad
        const float* xr = x + (size_t)i * 30;
        float xv[30];
        #pragma unroll
        for (int f = 0; f < 30; f++) xv[f] = xr[f];
        float r[4];
        #pragma unroll
        for (int cc = 0; cc < 4; cc++){
            int c = q4 * 4 + cc;
            const float* wr = &sW[c * 30];
            float s = sB[c];
            #pragma unroll
            for (int f = 0; f < 30; f++) s += xv[f] * wr[f];
            r[cc] = fmaxf(s, 0.f);
        }
        *(float4*)(h + (size_t)i * 32 + q4 * 4) = *(float4*)r;
        halfT rh[4];
        #pragma unroll
        for (int cc = 0; cc < 4; cc++) rh[cc] = (halfT)r[cc];
        *(uint2*)(hH + (size_t)i * 32 + q4 * 4) = *(uint2*)rh;
    } else if (b < 7506){
        __shared__ float sW1[128 * 11];
        __shared__ float sb1[128];
        for (int idx = tid; idx < 1408; idx += 256) sW1[idx] = W1[idx];
        if (tid < 128) sb1[tid] = b1[tid];
        __syncthreads();
        int t8 = (b - 1250) * 256 + tid;    // [0, NEP*16)
        int ch = t8 & 63;
        int s4 = (t8 >> 6) & 3;
        int g16 = t8 >> 8;
        int m = ch & 15, q = ch >> 4;       // lane-linear content
        int e = g16 * 16 + m;
        int kb = 32 * s4 + q * 8;
        halfT v[8];
        if (e < NE){
            const float* xr = ea + (size_t)e * 11;
            float xv[11];
            #pragma unroll
            for (int f = 0; f < 11; f++) xv[f] = xr[f];
            #pragma unroll
            for (int i8 = 0; i8 < 8; i8++){
                int k = kb + i8;
                const float* wr = &sW1[k * 11];
                float s = sb1[k];
                #pragma unroll
                for (int f = 0; f < 11; f++) s += xv[f] * wr[f];
                v[i8] = (halfT)fmaxf(s, 0.f);
            }
        } else {
            #pragma unroll
            for (int i8 = 0; i8 < 8; i8++) v[i8] = (halfT)0.f;
        }
        *(half8*)(ehF + (size_t)t8 * 8) = *(half8*)v;
    } else if (b < 8022){
        int gid = (b - 7506) * 256 + tid;   // 129*2*64*8 = 132096
        int i8 = gid & 7;
        int ch = (gid >> 3) & 63;
        int nt = (gid >> 9) & 1;
        int ks = gid >> 10;
        int m = ch & 15, q = ch >> 4;       // lane-linear content
        int o = nt * 16 + m;
        float v;
        if (ks < 128){
            int c = ks >> 2;
            int k = 32 * (ks & 3) + q * 8 + i8;
            v = W2[(size_t)(c * 32 + o) * 128 + k];
        } else {
            int c = q * 8 + i8;
            v = b2[c * 32 + o];
        }
        BfF[gid] = (halfT)v;
    } else if (b < 8413){
        int e = (b - 8022) * 256 + tid;
        if (e < NE) atomicAdd(&deg[dstA[e]], 1.f);
    } else if (b < 8493){
        int t = (b - 8413) * 256 + tid;     // 20480
        if (t < 3072){ int k = t / 96, j = t % 96; WgT[t] = gWih[(size_t)j * 32 + k]; }
        else if (t < 6144){ int t2 = t - 3072; int k = t2 / 96, j = t2 % 96; WhT[t2] = gWhh[(size_t)j * 32 + k]; }
        else if (t < 14336){ int t2 = t - 6144; int k = t2 >> 7, j = t2 & 127; lWihT[t2] = lWih[(size_t)j * 64 + k]; }
        else if (t < 18432){ int t2 = t - 14336; int k = t2 >> 7, j = t2 & 127; lWhhT[t2] = lWhh[(size_t)j * 32 + k]; }
        else { int t2 = t - 18432; int k = t2 >> 5, c = t2 & 31; lin1T[t2] = lin1_W[(size_t)c * 64 + k]; }
    } else {
        int g = (b - 8493) * 256 + tid;
        if (g > NB) return;
        int lo = 0, hi = NN;
        while (lo < hi){
            int mid = (lo + hi) >> 1;
            if (batch[mid] < g) lo = mid + 1; else hi = mid;
        }
        starts[g] = lo;
    }
}

// =====================================================================
// k_msg4: 512-thread blocks, 8 waves share one LDS B staging.  [unchanged]
// =====================================================================
__global__ __launch_bounds__(512, 4) void k_msg4(
    const halfT* __restrict__ ehF, const halfT* __restrict__ BfF,
    const halfT* __restrict__ hH,
    const int* __restrict__ src, const int* __restrict__ dst,
    float* __restrict__ aggr)
{
    __shared__ halfT sB[2][8192];        // 2 x 16KB
    int tid = threadIdx.x;               // 0..511
    int l = tid & 63;
    int wid = blockIdx.x * 8 + (tid >> 6);
    int m = l & 15, q = l >> 4;
    int eb = wid * 32;
    half8 pre[2];
    #pragma unroll
    for (int p = 0; p < 2; p++)
        pre[p] = *(const half8*)(BfF + (size_t)(p * 512 + tid) * 8);
    #pragma unroll
    for (int p = 0; p < 2; p++)
        *(half8*)(&sB[0][(p * 512 + tid) * 8]) = pre[p];
    half8 u0[4], u1[4], ub0, ub1;
    {
        int e0 = eb + m;      int se0 = (e0 < NE) ? src[e0] : 0;
        int e1 = eb + 16 + m; int se1 = (e1 < NE) ? src[e1] : 0;
        const halfT* p0 = hH + (size_t)se0 * 32;
        const halfT* p1 = hH + (size_t)se1 * 32;
        #pragma unroll
        for (int j = 0; j < 4; j++){
            u0[j] = *(const half8*)(p0 + j * 8);
            u1[j] = *(const half8*)(p1 + j * 8);
        }
        ub0 = *(const half8*)(p0 + q * 8);
        ub1 = *(const half8*)(p1 + q * 8);
    }
    half8 eh0[4], eh1[4];
    {
        int g0 = eb >> 4;
        #pragma unroll
        for (int s = 0; s < 4; s++){
            eh0[s] = *(const half8*)(ehF + ((size_t)(g0 * 4 + s) * 64 + l) * 8);
            eh1[s] = *(const half8*)(ehF + ((size_t)((g0 + 1) * 4 + s) * 64 + l) * 8);
        }
    }
    __syncthreads();
    #pragma unroll
    for (int p = 0; p < 2; p++)
        pre[p] = *(const half8*)(BfF + (size_t)8192 + (size_t)(p * 512 + tid) * 8);
    f32x4 acc00 = {0,0,0,0}, acc01 = {0,0,0,0}, acc10 = {0,0,0,0}, acc11 = {0,0,0,0};
    #pragma unroll
    for (int g = 0; g < 16; g++){
        const int cur = g & 1;
        #pragma unroll
        for (int j = 0; j < 8; j++){
            const int ks = g * 8 + j;
            half8 b0 = *(const half8*)(&sB[cur][(j * 2 + 0) * 512 + l * 8]);
            half8 b1 = *(const half8*)(&sB[cur][(j * 2 + 1) * 512 + l * 8]);
            const int c = ks >> 2, s = ks & 3;
            halfT uc0 = u0[c >> 3][c & 7];
            halfT uc1 = u1[c >> 3][c & 7];
            half8 a0 = eh0[s] * uc0;
            half8 a1 = eh1[s] * uc1;
            acc00 = __builtin_amdgcn_mfma_f32_16x16x32_f16(a0, b0, acc00, 0, 0, 0);
            acc01 = __builtin_amdgcn_mfma_f32_16x16x32_f16(a0, b1, acc01, 0, 0, 0);
            acc10 = __builtin_amdgcn_mfma_f32_16x16x32_f16(a1, b0, acc10, 0, 0, 0);
            acc11 = __builtin_amdgcn_mfma_f32_16x16x32_f16(a1, b1, acc11, 0, 0, 0);
        }
        if (g + 1 < 16){
            #pragma unroll
            for (int p = 0; p < 2; p++)
                *(half8*)(&sB[cur ^ 1][(p * 512 + tid) * 8]) = pre[p];
            if (g + 2 < 16){
                #pragma unroll
                for (int p = 0; p < 2; p++)
                    pre[p] = *(const half8*)(BfF + (size_t)(g + 2) * 8192 + (size_t)(p * 512 + tid) * 8);
            }
        }
        __syncthreads();
    }
    {
        half8 b0 = *(const half8*)(BfF + (size_t)256 * 512 + l * 8);
        half8 b1 = *(const half8*)(BfF + (size_t)257 * 512 + l * 8);
        acc00 = __builtin_amdgcn_mfma_f32_16x16x32_f16(ub0, b0, acc00, 0, 0, 0);
        acc01 = __builtin_amdgcn_mfma_f32_16x16x32_f16(ub0, b1, acc01, 0, 0, 0);
        acc10 = __builtin_amdgcn_mfma_f32_16x16x32_f16(ub1, b0, acc10, 0, 0, 0);
        acc11 = __builtin_amdgcn_mfma_f32_16x16x32_f16(ub1, b1, acc11, 0, 0, 0);
    }
    #pragma unroll
    for (int r = 0; r < 4; r++){
        int ea0 = eb + q * 4 + r;
        if (ea0 < NE){
            int d = dst[ea0];
            atomicAdd(&aggr[(size_t)d * 32 + m],      acc00[r]);
            atomicAdd(&aggr[(size_t)d * 32 + 16 + m], acc01[r]);
        }
        int ea1 = eb + 16 + q * 4 + r;
        if (ea1 < NE){
            int d = dst[ea1];
            atomicAdd(&aggr[(size_t)d * 32 + m],      acc10[r]);
            atomicAdd(&aggr[(size_t)d * 32 + 16 + m], acc11[r]);
        }
    }
}

// =====================================================================
// k_gru R14: LDS-staged weights + restored occupancy:
// 512 threads, 32 nodes/block (2 passes x 16), 1250 blocks ->
// ~4.9 blocks/CU x 8 waves -> full 32 waves/CU (vs R13's 625 blocks @ 18%).
// =====================================================================
__global__ __launch_bounds__(512, 8) void k_gru(
    float* __restrict__ aggr, const float* __restrict__ deg, float* __restrict__ h,
    halfT* __restrict__ hH,
    const float* __restrict__ rootW, const float* __restrict__ cb,
    const float* __restrict__ WgT, const float* __restrict__ WhT,
    const float* __restrict__ gbih, const float* __restrict__ gbhh)
{
    __shared__ float sR[1024];          // rootW [k*32+c]
    __shared__ float sG[3072];          // WgT   [k*96+j]
    __shared__ float sHW[3072];         // WhT   [k*96+j]
    __shared__ float sb[224];           // gbih(96) gbhh(96) cb(32)
    int tid = threadIdx.x;              // 0..511
    for (int i2 = tid; i2 < 1024; i2 += 512) sR[i2] = rootW[i2];
    for (int i2 = tid; i2 < 3072; i2 += 512){ sG[i2] = WgT[i2]; sHW[i2] = WhT[i2]; }
    if (tid < 96){ sb[tid] = gbih[tid]; sb[96 + tid] = gbhh[tid]; }
    if (tid >= 96 && tid < 128) sb[96 + tid] = cb[tid - 96];   // sb[192..223] = cb
    __syncthreads();
    int c = tid & 31;
    #pragma unroll
    for (int p = 0; p < 2; p++){
        int i = blockIdx.x * 32 + p * 16 + (tid >> 5);
        size_t base = (size_t)i * 32 + c;
        float hq = h[base];
        float av = aggr[base];
        aggr[base] = 0.f;
        float invd = 1.f / fmaxf(deg[i], 1.f);
        float mv = av * invd + sb[192 + c];
        #pragma unroll 8
        for (int k = 0; k < 32; k++)
            mv += __shfl(hq, k, 32) * sR[k * 32 + c];
        mv = fmaxf(mv, 0.f);
        float gr = sb[c],      hr = sb[96 + c];
        float gz = sb[32 + c], hz = sb[128 + c];
        float gn = sb[64 + c], hn = sb[160 + c];
        #pragma unroll 4
        for (int k = 0; k < 32; k++){
            float mk = __shfl(mv, k, 32);
            float hk = __shfl(hq, k, 32);
            const float* wg = &sG[k * 96];
            const float* wh = &sHW[k * 96];
            gr += mk * wg[c];      hr += hk * wh[c];
            gz += mk * wg[32 + c]; hz += hk * wh[32 + c];
            gn += mk * wg[64 + c]; hn += hk * wh[64 + c];
        }
        float r = sigf(gr + hr);
        float z = sigf(gz + hz);
        float n = tanh_f(gn + r * hn);
        float hnew = (1.f - z) * n + z * hq;
        h[base] = hnew;
        hH[base] = (halfT)hnew;
    }
}

// =====================================================================
// k_s2s: LDS-cached Set2Set + final MLP.  [unchanged]
// =====================================================================
__global__ __launch_bounds__(64) void k_s2s(
    const float* __restrict__ h, const int* __restrict__ starts,
    const float* __restrict__ lWihT, const float* __restrict__ lWhhT,
    const float* __restrict__ lbih, const float* __restrict__ lbhh,
    const float* __restrict__ lin1T, const float* __restrict__ lin1_b,
    const float* __restrict__ lin2W, const float* __restrict__ lin2b,
    float* __restrict__ e_buf, float* __restrict__ out)
{
    __shared__ float hl[MAXN * 33];
    __shared__ float al[MAXN];
    __shared__ float hsl[32];
    int g = blockIdx.x, l = threadIdx.x;
    int s0 = starts[g], s1 = starts[g + 1];
    int n = s1 - s0;
    int c = l & 31, grp = l >> 5;
    int nl = (n < MAXN) ? n : MAXN;
    for (int idx = l; idx < nl * 32; idx += 64)
        hl[(idx >> 5) * 33 + (idx & 31)] = h[(size_t)s0 * 32 + idx];
    __syncthreads();
    float qs = 0.f, hsv = 0.f, csv = 0.f;
    for (int t = 0; t < 3; t++){
        float a1 = lbih[l] + lbhh[l];
        float a2 = lbih[l + 64] + lbhh[l + 64];
        #pragma unroll 8
        for (int k = 0; k < 64; k++){
            float qk = __shfl(qs, k);
            a1 += qk * lWihT[k * 128 + l];
            a2 += qk * lWihT[k * 128 + 64 + l];
        }
        #pragma unroll 8
        for (int k = 0; k < 32; k++){
            float hk = __shfl(qs, k);
            a1 += hk * lWhhT[k * 128 + l];
            a2 += hk * lWhhT[k * 128 + 64 + l];
        }
        float gate1 = sigf(a1);
        float gate2 = (l < 32) ? tanhf(a2) : sigf(a2);
        float fv = __shfl(gate1, c + 32);
        float ov = __shfl(gate2, c + 32);
        if (l < 32){
            csv = fv * csv + gate1 * gate2;
            hsv = ov * tanhf(csv);
            hsl[l] = hsv;
        }
        __syncthreads();
        float lmax = -3.4e38f;
        for (int i = l; i < n; i += 64){
            const float* hr = (i < MAXN) ? &hl[i * 33] : &h[(size_t)(s0 + i) * 32];
            float p = 0.f;
            #pragma unroll
            for (int c2 = 0; c2 < 32; c2++) p += hr[c2] * hsl[c2];
            if (i < MAXN) al[i] = p; else e_buf[s0 + i] = p;
            lmax = fmaxf(lmax, p);
        }
        #pragma unroll
        for (int o = 1; o < 64; o <<= 1) lmax = fmaxf(lmax, __shfl_xor(lmax, o));
        float lsum = 0.f;
        for (int i = l; i < n; i += 64){
            float e = (i < MAXN) ? al[i] : e_buf[s0 + i];
            float a = expf(e - lmax);
            if (i < MAXN) al[i] = a; else e_buf[s0 + i] = a;
            lsum += a;
        }
        #pragma unroll
        for (int o = 1; o < 64; o <<= 1) lsum += __shfl_xor(lsum, o);
        float inv = (lsum > 0.f) ? 1.f / lsum : 0.f;
        __syncthreads();
        float acc = 0.f;
        for (int i = grp; i < n; i += 2){
            float a = (i < MAXN) ? al[i] : e_buf[s0 + i];
            const float* hr = (i < MAXN) ? &hl[i * 33] : &h[(size_t)(s0 + i) * 32];
            acc += a * hr[c];
        }
        acc *= inv;
        acc += __shfl_xor(acc, 32);
        qs = (l < 32) ? hsv : acc;
        __syncthreads();
    }
    float s = lin1_b[c];
    #pragma unroll 8
    for (int k = 0; k < 64; k++){
        float qk = __shfl(qs, k);
        s += qk * lin1T[k * 32 + c];
    }
    float pp = (l < 32) ? fmaxf(s, 0.f) * lin2W[c] : 0.f;
    pp += __shfl_xor(pp, 1);  pp += __shfl_xor(pp, 2);
    pp += __shfl_xor(pp, 4);  pp += __shfl_xor(pp, 8);
    pp += __shfl_xor(pp, 16); pp += __shfl_xor(pp, 32);
    if (l == 0) out[g] = pp + lin2b[0];
}

extern "C" void kernel_launch(void* const* d_in, const int* in_sizes, int n_in,
                              void* d_out, int out_size, void* d_ws, size_t ws_size,
                              hipStream_t stream){
    (void)in_sizes; (void)n_in; (void)out_size;
    const float* x        = (const float*)d_in[0];
    const float* ea       = (const float*)d_in[1];
    const int*   ei       = (const int*)d_in[2];
    const int*   batch    = (const int*)d_in[3];
    const float* lin0_W   = (const float*)d_in[4];
    const float* lin0_b   = (const float*)d_in[5];
    const float* mlp_W1   = (const float*)d_in[6];
    const float* mlp_b1   = (const float*)d_in[7];
    const float* mlp_W2   = (const float*)d_in[8];
    const float* mlp_b2   = (const float*)d_in[9];
    const float* root_W   = (const float*)d_in[10];
    const float* conv_b   = (const float*)d_in[11];
    const float* gWih     = (const float*)d_in[12];
    const float* gWhh     = (const float*)d_in[13];
    const float* gbih     = (const float*)d_in[14];
    const float* gbhh     = (const float*)d_in[15];
    const float* lWih     = (const float*)d_in[16];
    const float* lWhh     = (const float*)d_in[17];
    const float* lbih     = (const float*)d_in[18];
    const float* lbhh     = (const float*)d_in[19];
    const float* lin1_W   = (const float*)d_in[20];
    const float* lin1_b   = (const float*)d_in[21];
    const float* lin2_W   = (const float*)d_in[22];
    const float* lin2_b   = (const float*)d_in[23];
    const int* src = ei;
    const int* dst = ei + NE;
    float* out = (float*)d_out;

    char* w = (char*)d_ws;
    size_t off = 0;
    auto alloc = [&](size_t bytes) -> void* {
        void* p = w + off;
        off = (off + bytes + 255) & ~(size_t)255;
        return p;
    };
    float* deg    = (float*)alloc((size_t)NN * 4);            // contiguous with aggr
    float* aggr   = (float*)alloc((size_t)NN * 32 * 4);
    float* h      = (float*)alloc((size_t)NN * 32 * 4);
    halfT* hH     = (halfT*)alloc((size_t)NN * 32 * 2);
    halfT* ehF    = (halfT*)alloc((size_t)NEP * 128 * 2);
    halfT* BfF    = (halfT*)alloc((size_t)129 * 2 * 64 * 8 * 2);
    int*   starts = (int*)alloc((size_t)(NB + 1) * 4);
    float* WgT    = (float*)alloc((size_t)3072 * 4);
    float* WhT    = (float*)alloc((size_t)3072 * 4);
    float* lWihT  = (float*)alloc((size_t)8192 * 4);
    float* lWhhT  = (float*)alloc((size_t)4096 * 4);
    float* lin1T  = (float*)alloc((size_t)2048 * 4);
    float* e_buf  = (float*)alloc((size_t)NN * 4);
    if (ws_size < off) return;   // cannot run

    hipMemsetAsync(deg, 0, (size_t)NN * 4 + (size_t)NN * 32 * 4, stream);

    k_setup<<<8498, 256, 0, stream>>>(x, lin0_W, lin0_b, ea, mlp_W1, mlp_b1,
        mlp_W2, mlp_b2, dst, batch, gWih, gWhh, lWih, lWhh, lin1_W,
        h, hH, ehF, BfF, deg, WgT, WhT, lWihT, lWhhT, lin1T, starts);

    for (int t = 0; t < 3; t++){
        k_msg4<<<NEP / 256, 512, 0, stream>>>(ehF, BfF, hH, src, dst, aggr);
        k_gru<<<NN / 32, 512, 0, stream>>>(aggr, deg, h, hH, root_W, conv_b,
                                           WgT, WhT, gbih, gbhh);
    }
    k_s2s<<<NB, 64, 0, stream>>>(h, starts, lWihT, lWhhT, lbih, lbhh,
                                 lin1T, lin1_b, lin2_W, lin2_b, e_buf, out);
}

// Round 16
// 273.450 us; speedup vs baseline: 1.1506x; 1.0310x over previous
//
#include <hip/hip_runtime.h>
#include <hip/hip_bf16.h>
#include <cstdint>

#define NN 40000
#define NE 100000
#define NEP 100096           // 32-aligned edge count
#define NB 1024
#define MAXN 192             // per-graph LDS node cache capacity

typedef _Float16 halfT;
typedef _Float16 half8 __attribute__((ext_vector_type(8)));
typedef float f32x4 __attribute__((ext_vector_type(4)));

static __device__ __forceinline__ float sigf(float x){ return 1.f/(1.f + __expf(-x)); }
static __device__ __forceinline__ float tanh_f(float x){ float e = __expf(2.f * x); return 1.f - 2.f/(e + 1.f); }

// =====================================================================
// k_setup: one kernel, 6 block-ranges (all vectorized)  [unchanged]
// =====================================================================
__global__ __launch_bounds__(256) void k_setup(
    const float* __restrict__ x, const float* __restrict__ lin0_W, const float* __restrict__ lin0_b,
    const float* __restrict__ ea, const float* __restrict__ W1, const float* __restrict__ b1,
    const float* __restrict__ W2, const float* __restrict__ b2,
    const int* __restrict__ dstA, const int* __restrict__ batch,
    const float* __restrict__ gWih, const float* __restrict__ gWhh,
    const float* __restrict__ lWih, const float* __restrict__ lWhh, const float* __restrict__ lin1_W,
    float* __restrict__ h, halfT* __restrict__ hH, halfT* __restrict__ ehF, halfT* __restrict__ BfF,
    float* __restrict__ deg, float* __restrict__ WgT, float* __restrict__ WhT,
    float* __restrict__ lWihT, float* __restrict__ lWhhT, float* __restrict__ lin1T,
    int* __restrict__ starts)
{
    int b = blockIdx.x, tid = threadIdx.x;
    if (b < 1250){
        __shared__ float sW[32 * 30];
        __shared__ float sB[32];
        for (int idx = tid; idx < 960; idx += 256) sW[idx] = lin0_W[idx];
        if (tid < 32) sB[tid] = lin0_b[tid];
        __syncthreads();
        int t8 = b * 256 + tid;             // [0, NN*8)
        int i = t8 >> 3, q4 = t8 & 7;       // node, channel-quad
        const float* xr = x + (size_t)i * 30;
        float xv[30];
        #pragma unroll
        for (int f = 0; f < 30; f++) xv[f] = xr[f];
        float r[4];
        #pragma unroll
        for (int cc = 0; cc < 4; cc++){
            int c = q4 * 4 + cc;
            const float* wr = &sW[c * 30];
            float s = sB[c];
            #pragma unroll
            for (int f = 0; f < 30; f++) s += xv[f] * wr[f];
            r[cc] = fmaxf(s, 0.f);
        }
        *(float4*)(h + (size_t)i * 32 + q4 * 4) = *(float4*)r;
        halfT rh[4];
        #pragma unroll
        for (int cc = 0; cc < 4; cc++) rh[cc] = (halfT)r[cc];
        *(uint2*)(hH + (size_t)i * 32 + q4 * 4) = *(uint2*)rh;
    } else if (b < 7506){
        __shared__ float sW1[128 * 11];
        __shared__ float sb1[128];
        for (int idx = tid; idx < 1408; idx += 256) sW1[idx] = W1[idx];
        if (tid < 128) sb1[tid] = b1[tid];
        __syncthreads();
        int t8 = (b - 1250) * 256 + tid;    // [0, NEP*16)
        int ch = t8 & 63;
        int s4 = (t8 >> 6) & 3;
        int g16 = t8 >> 8;
        int m = ch & 15, q = ch >> 4;       // lane-linear content
        int e = g16 * 16 + m;
        int kb = 32 * s4 + q * 8;
        halfT v[8];
        if (e < NE){
            const float* xr = ea + (size_t)e * 11;
            float xv[11];
            #pragma unroll
            for (int f = 0; f < 11; f++) xv[f] = xr[f];
            #pragma unroll
            for (int i8 = 0; i8 < 8; i8++){
                int k = kb + i8;
                const float* wr = &sW1[k * 11];
                float s = sb1[k];
                #pragma unroll
                for (int f = 0; f < 11; f++) s += xv[f] * wr[f];
                v[i8] = (halfT)fmaxf(s, 0.f);
            }
        } else {
            #pragma unroll
            for (int i8 = 0; i8 < 8; i8++) v[i8] = (halfT)0.f;
        }
        *(half8*)(ehF + (size_t)t8 * 8) = *(half8*)v;
    } else if (b < 8022){
        int gid = (b - 7506) * 256 + tid;   // 129*2*64*8 = 132096
        int i8 = gid & 7;
        int ch = (gid >> 3) & 63;
        int nt = (gid >> 9) & 1;
        int ks = gid >> 10;
        int m = ch & 15, q = ch >> 4;       // lane-linear content
        int o = nt * 16 + m;
        float v;
        if (ks < 128){
            int c = ks >> 2;
            int k = 32 * (ks & 3) + q * 8 + i8;
            v = W2[(size_t)(c * 32 + o) * 128 + k];
        } else {
            int c = q * 8 + i8;
            v = b2[c * 32 + o];
        }
        BfF[gid] = (halfT)v;
    } else if (b < 8413){
        int e = (b - 8022) * 256 + tid;
        if (e < NE) atomicAdd(&deg[dstA[e]], 1.f);
    } else if (b < 8493){
        int t = (b - 8413) * 256 + tid;     // 20480
        if (t < 3072){ int k = t / 96, j = t % 96; WgT[t] = gWih[(size_t)j * 32 + k]; }
        else if (t < 6144){ int t2 = t - 3072; int k = t2 / 96, j = t2 % 96; WhT[t2] = gWhh[(size_t)j * 32 + k]; }
        else if (t < 14336){ int t2 = t - 6144; int k = t2 >> 7, j = t2 & 127; lWihT[t2] = lWih[(size_t)j * 64 + k]; }
        else if (t < 18432){ int t2 = t - 14336; int k = t2 >> 7, j = t2 & 127; lWhhT[t2] = lWhh[(size_t)j * 32 + k]; }
        else { int t2 = t - 18432; int k = t2 >> 5, c = t2 & 31; lin1T[t2] = lin1_W[(size_t)c * 64 + k]; }
    } else {
        int g = (b - 8493) * 256 + tid;
        if (g > NB) return;
        int lo = 0, hi = NN;
        while (lo < hi){
            int mid = (lo + hi) >> 1;
            if (batch[mid] < g) lo = mid + 1; else hi = mid;
        }
        starts[g] = lo;
    }
}

// =====================================================================
// k_msg4: 512-thread blocks, 8 waves share one LDS B staging.  [unchanged]
// =====================================================================
__global__ __launch_bounds__(512, 4) void k_msg4(
    const halfT* __restrict__ ehF, const halfT* __restrict__ BfF,
    const halfT* __restrict__ hH,
    const int* __restrict__ src, const int* __restrict__ dst,
    float* __restrict__ aggr)
{
    __shared__ halfT sB[2][8192];        // 2 x 16KB
    int tid = threadIdx.x;               // 0..511
    int l = tid & 63;
    int wid = blockIdx.x * 8 + (tid >> 6);
    int m = l & 15, q = l >> 4;
    int eb = wid * 32;
    half8 pre[2];
    #pragma unroll
    for (int p = 0; p < 2; p++)
        pre[p] = *(const half8*)(BfF + (size_t)(p * 512 + tid) * 8);
    #pragma unroll
    for (int p = 0; p < 2; p++)
        *(half8*)(&sB[0][(p * 512 + tid) * 8]) = pre[p];
    half8 u0[4], u1[4], ub0, ub1;
    {
        int e0 = eb + m;      int se0 = (e0 < NE) ? src[e0] : 0;
        int e1 = eb + 16 + m; int se1 = (e1 < NE) ? src[e1] : 0;
        const halfT* p0 = hH + (size_t)se0 * 32;
        const halfT* p1 = hH + (size_t)se1 * 32;
        #pragma unroll
        for (int j = 0; j < 4; j++){
            u0[j] = *(const half8*)(p0 + j * 8);
            u1[j] = *(const half8*)(p1 + j * 8);
        }
        ub0 = *(const half8*)(p0 + q * 8);
        ub1 = *(const half8*)(p1 + q * 8);
    }
    half8 eh0[4], eh1[4];
    {
        int g0 = eb >> 4;
        #pragma unroll
        for (int s = 0; s < 4; s++){
            eh0[s] = *(const half8*)(ehF + ((size_t)(g0 * 4 + s) * 64 + l) * 8);
            eh1[s] = *(const half8*)(ehF + ((size_t)((g0 + 1) * 4 + s) * 64 + l) * 8);
        }
    }
    __syncthreads();
    #pragma unroll
    for (int p = 0; p < 2; p++)
        pre[p] = *(const half8*)(BfF + (size_t)8192 + (size_t)(p * 512 + tid) * 8);
    f32x4 acc00 = {0,0,0,0}, acc01 = {0,0,0,0}, acc10 = {0,0,0,0}, acc11 = {0,0,0,0};
    #pragma unroll
    for (int g = 0; g < 16; g++){
        const int cur = g & 1;
        #pragma unroll
        for (int j = 0; j < 8; j++){
            const int ks = g * 8 + j;
            half8 b0 = *(const half8*)(&sB[cur][(j * 2 + 0) * 512 + l * 8]);
            half8 b1 = *(const half8*)(&sB[cur][(j * 2 + 1) * 512 + l * 8]);
            const int c = ks >> 2, s = ks & 3;
            halfT uc0 = u0[c >> 3][c & 7];
            halfT uc1 = u1[c >> 3][c & 7];
            half8 a0 = eh0[s] * uc0;
            half8 a1 = eh1[s] * uc1;
            acc00 = __builtin_amdgcn_mfma_f32_16x16x32_f16(a0, b0, acc00, 0, 0, 0);
            acc01 = __builtin_amdgcn_mfma_f32_16x16x32_f16(a0, b1, acc01, 0, 0, 0);
            acc10 = __builtin_amdgcn_mfma_f32_16x16x32_f16(a1, b0, acc10, 0, 0, 0);
            acc11 = __builtin_amdgcn_mfma_f32_16x16x32_f16(a1, b1, acc11, 0, 0, 0);
        }
        if (g + 1 < 16){
            #pragma unroll
            for (int p = 0; p < 2; p++)
                *(half8*)(&sB[cur ^ 1][(p * 512 + tid) * 8]) = pre[p];
            if (g + 2 < 16){
                #pragma unroll
                for (int p = 0; p < 2; p++)
                    pre[p] = *(const half8*)(BfF + (size_t)(g + 2) * 8192 + (size_t)(p * 512 + tid) * 8);
            }
        }
        __syncthreads();
    }
    {
        half8 b0 = *(const half8*)(BfF + (size_t)256 * 512 + l * 8);
        half8 b1 = *(const half8*)(BfF + (size_t)257 * 512 + l * 8);
        acc00 = __builtin_amdgcn_mfma_f32_16x16x32_f16(ub0, b0, acc00, 0, 0, 0);
        acc01 = __builtin_amdgcn_mfma_f32_16x16x32_f16(ub0, b1, acc01, 0, 0, 0);
        acc10 = __builtin_amdgcn_mfma_f32_16x16x32_f16(ub1, b0, acc10, 0, 0, 0);
        acc11 = __builtin_amdgcn_mfma_f32_16x16x32_f16(ub1, b1, acc11, 0, 0, 0);
    }
    #pragma unroll
    for (int r = 0; r < 4; r++){
        int ea0 = eb + q * 4 + r;
        if (ea0 < NE){
            int d = dst[ea0];
            atomicAdd(&aggr[(size_t)d * 32 + m],      acc00[r]);
            atomicAdd(&aggr[(size_t)d * 32 + 16 + m], acc01[r]);
        }
        int ea1 = eb + 16 + q * 4 + r;
        if (ea1 < NE){
            int d = dst[ea1];
            atomicAdd(&aggr[(size_t)d * 32 + m],      acc10[r]);
            atomicAdd(&aggr[(size_t)d * 32 + 16 + m], acc11[r]);
        }
    }
}

// =====================================================================
// k_gru R16: LANE-PER-NODE. h-row + mv in registers (full unroll, static
// indices), weights via wave-uniform LDS broadcast reads (no shfl, no
// bank conflicts). Gate math in 4 j-blocks of 8 to bound registers.
// Arithmetic order identical to R14/R15 (k-ascending) -> same absmax.
// =====================================================================
__global__ __launch_bounds__(256) void k_gru(
    float* __restrict__ aggr, const float* __restrict__ deg, float* __restrict__ h,
    halfT* __restrict__ hH,
    const float* __restrict__ rootW, const float* __restrict__ cb,
    const float* __restrict__ WgT, const float* __restrict__ WhT,
    const float* __restrict__ gbih, const float* __restrict__ gbhh)
{
    __shared__ float sR[1024];          // rootW [k*32+c]
    __shared__ float sG[3072];          // WgT   [k*96+j]
    __shared__ float sHW[3072];         // WhT   [k*96+j]
    __shared__ float sb[224];           // gbih(96) gbhh(96) cb(32)
    int tid = threadIdx.x;
    for (int i2 = tid; i2 < 1024; i2 += 256) sR[i2] = rootW[i2];
    for (int i2 = tid; i2 < 3072; i2 += 256){ sG[i2] = WgT[i2]; sHW[i2] = WhT[i2]; }
    if (tid < 96){ sb[tid] = gbih[tid]; sb[96 + tid] = gbhh[tid]; }
    if (tid >= 96 && tid < 128) sb[96 + tid] = cb[tid - 96];   // sb[192..223] = cb
    __syncthreads();
    int i = blockIdx.x * 256 + tid;
    if (i >= NN) return;
    size_t base = (size_t)i * 32;
    float hq[32], mv[32];
    #pragma unroll
    for (int k = 0; k < 8; k++) *(float4*)&hq[k * 4] = *(const float4*)(h + base + k * 4);
    float invd = 1.f / fmaxf(deg[i], 1.f);
    const float4 z4 = make_float4(0.f, 0.f, 0.f, 0.f);
    #pragma unroll
    for (int k = 0; k < 8; k++){
        float4 av = *(const float4*)(aggr + base + k * 4);
        mv[k * 4 + 0] = av.x * invd + sb[192 + k * 4 + 0];
        mv[k * 4 + 1] = av.y * invd + sb[192 + k * 4 + 1];
        mv[k * 4 + 2] = av.z * invd + sb[192 + k * 4 + 2];
        mv[k * 4 + 3] = av.w * invd + sb[192 + k * 4 + 3];
        *(float4*)(aggr + base + k * 4) = z4;           // re-zero for next iter
    }
    // mv += h @ rootW  (k ascending, same order as R15)
    #pragma unroll
    for (int k = 0; k < 32; k++){
        float hk = hq[k];
        #pragma unroll
        for (int c4 = 0; c4 < 8; c4++){
            float4 wv = *(const float4*)&sR[k * 32 + c4 * 4];
            mv[c4 * 4 + 0] += hk * wv.x;
            mv[c4 * 4 + 1] += hk * wv.y;
            mv[c4 * 4 + 2] += hk * wv.z;
            mv[c4 * 4 + 3] += hk * wv.w;
        }
    }
    #pragma unroll
    for (int c = 0; c < 32; c++) mv[c] = fmaxf(mv[c], 0.f);
    // gates in 4 blocks of 8 channels
    #pragma unroll
    for (int jg = 0; jg < 4; jg++){
        const int j0 = jg * 8;
        float gxr[8], ghr[8], gxz[8], ghz[8], gxn[8], ghn[8];
        #pragma unroll
        for (int j = 0; j < 8; j++){
            gxr[j] = sb[j0 + j];       ghr[j] = sb[96 + j0 + j];
            gxz[j] = sb[32 + j0 + j];  ghz[j] = sb[128 + j0 + j];
            gxn[j] = sb[64 + j0 + j];  ghn[j] = sb[160 + j0 + j];
        }
        #pragma unroll
        for (int k = 0; k < 32; k++){
            float mk = mv[k], hk = hq[k];
            const float* wg = &sG[k * 96];
            const float* wh = &sHW[k * 96];
            float4 r0 = *(const float4*)(wg + j0);       float4 r1 = *(const float4*)(wg + j0 + 4);
            float4 z0 = *(const float4*)(wg + 32 + j0);  float4 z1 = *(const float4*)(wg + 32 + j0 + 4);
            float4 n0 = *(const float4*)(wg + 64 + j0);  float4 n1 = *(const float4*)(wg + 64 + j0 + 4);
            float4 hr0 = *(const float4*)(wh + j0);      float4 hr1 = *(const float4*)(wh + j0 + 4);
            float4 hz0 = *(const float4*)(wh + 32 + j0); float4 hz1 = *(const float4*)(wh + 32 + j0 + 4);
            float4 hn0 = *(const float4*)(wh + 64 + j0); float4 hn1 = *(const float4*)(wh + 64 + j0 + 4);
            gxr[0] += mk * r0.x; gxr[1] += mk * r0.y; gxr[2] += mk * r0.z; gxr[3] += mk * r0.w;
            gxr[4] += mk * r1.x; gxr[5] += mk * r1.y; gxr[6] += mk * r1.z; gxr[7] += mk * r1.w;
            gxz[0] += mk * z0.x; gxz[1] += mk * z0.y; gxz[2] += mk * z0.z; gxz[3] += mk * z0.w;
            gxz[4] += mk * z1.x; gxz[5] += mk * z1.y; gxz[6] += mk * z1.z; gxz[7] += mk * z1.w;
            gxn[0] += mk * n0.x; gxn[1] += mk * n0.y; gxn[2] += mk * n0.z; gxn[3] += mk * n0.w;
            gxn[4] += mk * n1.x; gxn[5] += mk * n1.y; gxn[6] += mk * n1.z; gxn[7] += mk * n1.w;
            ghr[0] += hk * hr0.x; ghr[1] += hk * hr0.y; ghr[2] += hk * hr0.z; ghr[3] += hk * hr0.w;
            ghr[4] += hk * hr1.x; ghr[5] += hk * hr1.y; ghr[6] += hk * hr1.z; ghr[7] += hk * hr1.w;
            ghz[0] += hk * hz0.x; ghz[1] += hk * hz0.y; ghz[2] += hk * hz0.z; ghz[3] += hk * hz0.w;
            ghz[4] += hk * hz1.x; ghz[5] += hk * hz1.y; ghz[6] += hk * hz1.z; ghz[7] += hk * hz1.w;
            ghn[0] += hk * hn0.x; ghn[1] += hk * hn0.y; ghn[2] += hk * hn0.z; ghn[3] += hk * hn0.w;
            ghn[4] += hk * hn1.x; ghn[5] += hk * hn1.y; ghn[6] += hk * hn1.z; ghn[7] += hk * hn1.w;
        }
        float hn8[8];
        halfT hh8[8];
        #pragma unroll
        for (int j = 0; j < 8; j++){
            float r = sigf(gxr[j] + ghr[j]);
            float z = sigf(gxz[j] + ghz[j]);
            float n = tanh_f(gxn[j] + r * ghn[j]);
            hn8[j] = (1.f - z) * n + z * hq[j0 + j];
            hh8[j] = (halfT)hn8[j];
        }
        *(float4*)(h + base + j0)     = *(float4*)&hn8[0];
        *(float4*)(h + base + j0 + 4) = *(float4*)&hn8[4];
        *(half8*)(hH + base + j0)     = *(half8*)hh8;
    }
}

// =====================================================================
// k_s2s: LDS-cached Set2Set + final MLP.  [unchanged]
// =====================================================================
__global__ __launch_bounds__(64) void k_s2s(
    const float* __restrict__ h, const int* __restrict__ starts,
    const float* __restrict__ lWihT, const float* __restrict__ lWhhT,
    const float* __restrict__ lbih, const float* __restrict__ lbhh,
    const float* __restrict__ lin1T, const float* __restrict__ lin1_b,
    const float* __restrict__ lin2W, const float* __restrict__ lin2b,
    float* __restrict__ e_buf, float* __restrict__ out)
{
    __shared__ float hl[MAXN * 33];
    __shared__ float al[MAXN];
    __shared__ float hsl[32];
    int g = blockIdx.x, l = threadIdx.x;
    int s0 = starts[g], s1 = starts[g + 1];
    int n = s1 - s0;
    int c = l & 31, grp = l >> 5;
    int nl = (n < MAXN) ? n : MAXN;
    for (int idx = l; idx < nl * 32; idx += 64)
        hl[(idx >> 5) * 33 + (idx & 31)] = h[(size_t)s0 * 32 + idx];
    __syncthreads();
    float qs = 0.f, hsv = 0.f, csv = 0.f;
    for (int t = 0; t < 3; t++){
        float a1 = lbih[l] + lbhh[l];
        float a2 = lbih[l + 64] + lbhh[l + 64];
        #pragma unroll 8
        for (int k = 0; k < 64; k++){
            float qk = __shfl(qs, k);
            a1 += qk * lWihT[k * 128 + l];
            a2 += qk * lWihT[k * 128 + 64 + l];
        }
        #pragma unroll 8
        for (int k = 0; k < 32; k++){
            float hk = __shfl(qs, k);
            a1 += hk * lWhhT[k * 128 + l];
            a2 += hk * lWhhT[k * 128 + 64 + l];
        }
        float gate1 = sigf(a1);
        float gate2 = (l < 32) ? tanhf(a2) : sigf(a2);
        float fv = __shfl(gate1, c + 32);
        float ov = __shfl(gate2, c + 32);
        if (l < 32){
            csv = fv * csv + gate1 * gate2;
            hsv = ov * tanhf(csv);
            hsl[l] = hsv;
        }
        __syncthreads();
        float lmax = -3.4e38f;
        for (int i = l; i < n; i += 64){
            const float* hr = (i < MAXN) ? &hl[i * 33] : &h[(size_t)(s0 + i) * 32];
            float p = 0.f;
            #pragma unroll
            for (int c2 = 0; c2 < 32; c2++) p += hr[c2] * hsl[c2];
            if (i < MAXN) al[i] = p; else e_buf[s0 + i] = p;
            lmax = fmaxf(lmax, p);
        }
        #pragma unroll
        for (int o = 1; o < 64; o <<= 1) lmax = fmaxf(lmax, __shfl_xor(lmax, o));
        float lsum = 0.f;
        for (int i = l; i < n; i += 64){
            float e = (i < MAXN) ? al[i] : e_buf[s0 + i];
            float a = expf(e - lmax);
            if (i < MAXN) al[i] = a; else e_buf[s0 + i] = a;
            lsum += a;
        }
        #pragma unroll
        for (int o = 1; o < 64; o <<= 1) lsum += __shfl_xor(lsum, o);
        float inv = (lsum > 0.f) ? 1.f / lsum : 0.f;
        __syncthreads();
        float acc = 0.f;
        for (int i = grp; i < n; i += 2){
            float a = (i < MAXN) ? al[i] : e_buf[s0 + i];
            const float* hr = (i < MAXN) ? &hl[i * 33] : &h[(size_t)(s0 + i) * 32];
            acc += a * hr[c];
        }
        acc *= inv;
        acc += __shfl_xor(acc, 32);
        qs = (l < 32) ? hsv : acc;
        __syncthreads();
    }
    float s = lin1_b[c];
    #pragma unroll 8
    for (int k = 0; k < 64; k++){
        float qk = __shfl(qs, k);
        s += qk * lin1T[k * 32 + c];
    }
    float pp = (l < 32) ? fmaxf(s, 0.f) * lin2W[c] : 0.f;
    pp += __shfl_xor(pp, 1);  pp += __shfl_xor(pp, 2);
    pp += __shfl_xor(pp, 4);  pp += __shfl_xor(pp, 8);
    pp += __shfl_xor(pp, 16); pp += __shfl_xor(pp, 32);
    if (l == 0) out[g] = pp + lin2b[0];
}

extern "C" void kernel_launch(void* const* d_in, const int* in_sizes, int n_in,
                              void* d_out, int out_size, void* d_ws, size_t ws_size,
                              hipStream_t stream){
    (void)in_sizes; (void)n_in; (void)out_size;
    const float* x        = (const float*)d_in[0];
    const float* ea       = (const float*)d_in[1];
    const int*   ei       = (const int*)d_in[2];
    const int*   batch    = (const int*)d_in[3];
    const float* lin0_W   = (const float*)d_in[4];
    const float* lin0_b   = (const float*)d_in[5];
    const float* mlp_W1   = (const float*)d_in[6];
    const float* mlp_b1   = (const float*)d_in[7];
    const float* mlp_W2   = (const float*)d_in[8];
    const float* mlp_b2   = (const float*)d_in[9];
    const float* root_W   = (const float*)d_in[10];
    const float* conv_b   = (const float*)d_in[11];
    const float* gWih     = (const float*)d_in[12];
    const float* gWhh     = (const float*)d_in[13];
    const float* gbih     = (const float*)d_in[14];
    const float* gbhh     = (const float*)d_in[15];
    const float* lWih     = (const float*)d_in[16];
    const float* lWhh     = (const float*)d_in[17];
    const float* lbih     = (const float*)d_in[18];
    const float* lbhh     = (const float*)d_in[19];
    const float* lin1_W   = (const float*)d_in[20];
    const float* lin1_b   = (const float*)d_in[21];
    const float* lin2_W   = (const float*)d_in[22];
    const float* lin2_b   = (const float*)d_in[23];
    const int* src = ei;
    const int* dst = ei + NE;
    float* out = (float*)d_out;

    char* w = (char*)d_ws;
    size_t off = 0;
    auto alloc = [&](size_t bytes) -> void* {
        void* p = w + off;
        off = (off + bytes + 255) & ~(size_t)255;
        return p;
    };
    float* deg    = (float*)alloc((size_t)NN * 4);            // contiguous with aggr
    float* aggr   = (float*)alloc((size_t)NN * 32 * 4);
    float* h      = (float*)alloc((size_t)NN * 32 * 4);
    halfT* hH     = (halfT*)alloc((size_t)NN * 32 * 2);
    halfT* ehF    = (halfT*)alloc((size_t)NEP * 128 * 2);
    halfT* BfF    = (halfT*)alloc((size_t)129 * 2 * 64 * 8 * 2);
    int*   starts = (int*)alloc((size_t)(NB + 1) * 4);
    float* WgT    = (float*)alloc((size_t)3072 * 4);
    float* WhT    = (float*)alloc((size_t)3072 * 4);
    float* lWihT  = (float*)alloc((size_t)8192 * 4);
    float* lWhhT  = (float*)alloc((size_t)4096 * 4);
    float* lin1T  = (float*)alloc((size_t)2048 * 4);
    float* e_buf  = (float*)alloc((size_t)NN * 4);
    if (ws_size < off) return;   // cannot run

    hipMemsetAsync(deg, 0, (size_t)NN * 4 + (size_t)NN * 32 * 4, stream);

    k_setup<<<8498, 256, 0, stream>>>(x, lin0_W, lin0_b, ea, mlp_W1, mlp_b1,
        mlp_W2, mlp_b2, dst, batch, gWih, gWhh, lWih, lWhh, lin1_W,
        h, hH, ehF, BfF, deg, WgT, WhT, lWihT, lWhhT, lin1T, starts);

    for (int t = 0; t < 3; t++){
        k_msg4<<<NEP / 256, 512, 0, stream>>>(ehF, BfF, hH, src, dst, aggr);
        k_gru<<<(NN + 255) / 256, 256, 0, stream>>>(aggr, deg, h, hH, root_W, conv_b,
                                                    WgT, WhT, gbih, gbhh);
    }
    k_s2s<<<NB, 64, 0, stream>>>(h, starts, lWihT, lWhhT, lbih, lbhh,
                                 lin1T, lin1_b, lin2_W, lin2_b, e_buf, out);
}

// Round 17
// 184.756 us; speedup vs baseline: 1.7030x; 1.4801x over previous
//
#include <hip/hip_runtime.h>
#include <hip/hip_bf16.h>
#include <cstdint>

#define NN 40000
#define NE 100000
#define NEP 100096           // 32-aligned edge count
#define NB 1024
#define MAXN 192             // per-graph LDS node cache capacity

typedef _Float16 halfT;
typedef _Float16 half8 __attribute__((ext_vector_type(8)));
typedef float f32x4 __attribute__((ext_vector_type(4)));

static __device__ __forceinline__ float sigf(float x){ return 1.f/(1.f + __expf(-x)); }
static __device__ __forceinline__ float tanh_f(float x){ float e = __expf(2.f * x); return 1.f - 2.f/(e + 1.f); }

// =====================================================================
// k_setup: one kernel, 7 block-ranges.
// R6 (new): gateB — GRU weights prepacked into MFMA B-fragment tiles fp16.
//   gateB[tile][l][i]; tile 0-1: rootW c-tiles (val=rootW[k*32+c]);
//   tile 2-7: gWih j-tiles (val=gWih[j*32+k]); tile 8-13: gWhh j-tiles.
//   c/j = (tile-rel)*16 + (l&15), k = (l>>4)*8 + i.
// =====================================================================
__global__ __launch_bounds__(256) void k_setup(
    const float* __restrict__ x, const float* __restrict__ lin0_W, const float* __restrict__ lin0_b,
    const float* __restrict__ ea, const float* __restrict__ W1, const float* __restrict__ b1,
    const float* __restrict__ W2, const float* __restrict__ b2,
    const int* __restrict__ dstA, const int* __restrict__ batch,
    const float* __restrict__ rootW,
    const float* __restrict__ gWih, const float* __restrict__ gWhh,
    const float* __restrict__ lWih, const float* __restrict__ lWhh, const float* __restrict__ lin1_W,
    float* __restrict__ h, halfT* __restrict__ hH, halfT* __restrict__ ehF, halfT* __restrict__ BfF,
    float* __restrict__ deg, halfT* __restrict__ gateB,
    float* __restrict__ lWihT, float* __restrict__ lWhhT, float* __restrict__ lin1T,
    int* __restrict__ starts)
{
    int b = blockIdx.x, tid = threadIdx.x;
    if (b < 1250){
        __shared__ float sW[32 * 30];
        __shared__ float sB[32];
        for (int idx = tid; idx < 960; idx += 256) sW[idx] = lin0_W[idx];
        if (tid < 32) sB[tid] = lin0_b[tid];
        __syncthreads();
        int t8 = b * 256 + tid;             // [0, NN*8)
        int i = t8 >> 3, q4 = t8 & 7;       // node, channel-quad
        const float* xr = x + (size_t)i * 30;
        float xv[30];
        #pragma unroll
        for (int f = 0; f < 30; f++) xv[f] = xr[f];
        float r[4];
        #pragma unroll
        for (int cc = 0; cc < 4; cc++){
            int c = q4 * 4 + cc;
            const float* wr = &sW[c * 30];
            float s = sB[c];
            #pragma unroll
            for (int f = 0; f < 30; f++) s += xv[f] * wr[f];
            r[cc] = fmaxf(s, 0.f);
        }
        *(float4*)(h + (size_t)i * 32 + q4 * 4) = *(float4*)r;
        halfT rh[4];
        #pragma unroll
        for (int cc = 0; cc < 4; cc++) rh[cc] = (halfT)r[cc];
        *(uint2*)(hH + (size_t)i * 32 + q4 * 4) = *(uint2*)rh;
    } else if (b < 7506){
        __shared__ float sW1[128 * 11];
        __shared__ float sb1[128];
        for (int idx = tid; idx < 1408; idx += 256) sW1[idx] = W1[idx];
        if (tid < 128) sb1[tid] = b1[tid];
        __syncthreads();
        int t8 = (b - 1250) * 256 + tid;    // [0, NEP*16)
        int ch = t8 & 63;
        int s4 = (t8 >> 6) & 3;
        int g16 = t8 >> 8;
        int m = ch & 15, q = ch >> 4;       // lane-linear content
        int e = g16 * 16 + m;
        int kb = 32 * s4 + q * 8;
        halfT v[8];
        if (e < NE){
            const float* xr = ea + (size_t)e * 11;
            float xv[11];
            #pragma unroll
            for (int f = 0; f < 11; f++) xv[f] = xr[f];
            #pragma unroll
            for (int i8 = 0; i8 < 8; i8++){
                int k = kb + i8;
                const float* wr = &sW1[k * 11];
                float s = sb1[k];
                #pragma unroll
                for (int f = 0; f < 11; f++) s += xv[f] * wr[f];
                v[i8] = (halfT)fmaxf(s, 0.f);
            }
        } else {
            #pragma unroll
            for (int i8 = 0; i8 < 8; i8++) v[i8] = (halfT)0.f;
        }
        *(half8*)(ehF + (size_t)t8 * 8) = *(half8*)v;
    } else if (b < 8022){
        int gid = (b - 7506) * 256 + tid;   // 129*2*64*8 = 132096
        int i8 = gid & 7;
        int ch = (gid >> 3) & 63;
        int nt = (gid >> 9) & 1;
        int ks = gid >> 10;
        int m = ch & 15, q = ch >> 4;       // lane-linear content
        int o = nt * 16 + m;
        float v;
        if (ks < 128){
            int c = ks >> 2;
            int k = 32 * (ks & 3) + q * 8 + i8;
            v = W2[(size_t)(c * 32 + o) * 128 + k];
        } else {
            int c = q * 8 + i8;
            v = b2[c * 32 + o];
        }
        BfF[gid] = (halfT)v;
    } else if (b < 8413){
        int e = (b - 8022) * 256 + tid;
        if (e < NE) atomicAdd(&deg[dstA[e]], 1.f);
    } else if (b < 8493){
        int t = (b - 8413) * 256 + tid;     // 20480 (s2s weight transposes)
        if (t < 8192){ int k = t >> 7, j = t & 127; lWihT[t] = lWih[(size_t)j * 64 + k]; }
        else if (t < 12288){ int t2 = t - 8192; int k = t2 >> 7, j = t2 & 127; lWhhT[t2] = lWhh[(size_t)j * 32 + k]; }
        else if (t < 14336){ int t2 = t - 12288; int k = t2 >> 5, c = t2 & 31; lin1T[t2] = lin1_W[(size_t)c * 64 + k]; }
    } else if (b < 8498){
        int g = (b - 8493) * 256 + tid;
        if (g > NB) return;
        int lo = 0, hi = NN;
        while (lo < hi){
            int mid = (lo + hi) >> 1;
            if (batch[mid] < g) lo = mid + 1; else hi = mid;
        }
        starts[g] = lo;
    } else {
        int t = (b - 8498) * 256 + tid;     // 14*64*8 = 7168 gateB entries
        if (t >= 7168) return;
        int tile = t >> 9;
        int l = (t >> 3) & 63;
        int i = t & 7;
        int m = l & 15, q = l >> 4;
        int k = q * 8 + i;
        float v;
        if (tile < 2){
            int c = tile * 16 + m;
            v = rootW[(size_t)k * 32 + c];
        } else if (tile < 8){
            int j = (tile - 2) * 16 + m;
            v = gWih[(size_t)j * 32 + k];
        } else {
            int j = (tile - 8) * 16 + m;
            v = gWhh[(size_t)j * 32 + k];
        }
        gateB[t] = (halfT)v;
    }
}

// =====================================================================
// k_msg4: 512-thread blocks, 8 waves share one LDS B staging.  [unchanged]
// =====================================================================
__global__ __launch_bounds__(512, 4) void k_msg4(
    const halfT* __restrict__ ehF, const halfT* __restrict__ BfF,
    const halfT* __restrict__ hH,
    const int* __restrict__ src, const int* __restrict__ dst,
    float* __restrict__ aggr)
{
    __shared__ halfT sB[2][8192];        // 2 x 16KB
    int tid = threadIdx.x;               // 0..511
    int l = tid & 63;
    int wid = blockIdx.x * 8 + (tid >> 6);
    int m = l & 15, q = l >> 4;
    int eb = wid * 32;
    half8 pre[2];
    #pragma unroll
    for (int p = 0; p < 2; p++)
        pre[p] = *(const half8*)(BfF + (size_t)(p * 512 + tid) * 8);
    #pragma unroll
    for (int p = 0; p < 2; p++)
        *(half8*)(&sB[0][(p * 512 + tid) * 8]) = pre[p];
    half8 u0[4], u1[4], ub0, ub1;
    {
        int e0 = eb + m;      int se0 = (e0 < NE) ? src[e0] : 0;
        int e1 = eb + 16 + m; int se1 = (e1 < NE) ? src[e1] : 0;
        const halfT* p0 = hH + (size_t)se0 * 32;
        const halfT* p1 = hH + (size_t)se1 * 32;
        #pragma unroll
        for (int j = 0; j < 4; j++){
            u0[j] = *(const half8*)(p0 + j * 8);
            u1[j] = *(const half8*)(p1 + j * 8);
        }
        ub0 = *(const half8*)(p0 + q * 8);
        ub1 = *(const half8*)(p1 + q * 8);
    }
    half8 eh0[4], eh1[4];
    {
        int g0 = eb >> 4;
        #pragma unroll
        for (int s = 0; s < 4; s++){
            eh0[s] = *(const half8*)(ehF + ((size_t)(g0 * 4 + s) * 64 + l) * 8);
            eh1[s] = *(const half8*)(ehF + ((size_t)((g0 + 1) * 4 + s) * 64 + l) * 8);
        }
    }
    __syncthreads();
    #pragma unroll
    for (int p = 0; p < 2; p++)
        pre[p] = *(const half8*)(BfF + (size_t)8192 + (size_t)(p * 512 + tid) * 8);
    f32x4 acc00 = {0,0,0,0}, acc01 = {0,0,0,0}, acc10 = {0,0,0,0}, acc11 = {0,0,0,0};
    #pragma unroll
    for (int g = 0; g < 16; g++){
        const int cur = g & 1;
        #pragma unroll
        for (int j = 0; j < 8; j++){
            const int ks = g * 8 + j;
            half8 b0 = *(const half8*)(&sB[cur][(j * 2 + 0) * 512 + l * 8]);
            half8 b1 = *(const half8*)(&sB[cur][(j * 2 + 1) * 512 + l * 8]);
            const int c = ks >> 2, s = ks & 3;
            halfT uc0 = u0[c >> 3][c & 7];
            halfT uc1 = u1[c >> 3][c & 7];
            half8 a0 = eh0[s] * uc0;
            half8 a1 = eh1[s] * uc1;
            acc00 = __builtin_amdgcn_mfma_f32_16x16x32_f16(a0, b0, acc00, 0, 0, 0);
            acc01 = __builtin_amdgcn_mfma_f32_16x16x32_f16(a0, b1, acc01, 0, 0, 0);
            acc10 = __builtin_amdgcn_mfma_f32_16x16x32_f16(a1, b0, acc10, 0, 0, 0);
            acc11 = __builtin_amdgcn_mfma_f32_16x16x32_f16(a1, b1, acc11, 0, 0, 0);
        }
        if (g + 1 < 16){
            #pragma unroll
            for (int p = 0; p < 2; p++)
                *(half8*)(&sB[cur ^ 1][(p * 512 + tid) * 8]) = pre[p];
            if (g + 2 < 16){
                #pragma unroll
                for (int p = 0; p < 2; p++)
                    pre[p] = *(const half8*)(BfF + (size_t)(g + 2) * 8192 + (size_t)(p * 512 + tid) * 8);
            }
        }
        __syncthreads();
    }
    {
        half8 b0 = *(const half8*)(BfF + (size_t)256 * 512 + l * 8);
        half8 b1 = *(const half8*)(BfF + (size_t)257 * 512 + l * 8);
        acc00 = __builtin_amdgcn_mfma_f32_16x16x32_f16(ub0, b0, acc00, 0, 0, 0);
        acc01 = __builtin_amdgcn_mfma_f32_16x16x32_f16(ub0, b1, acc01, 0, 0, 0);
        acc10 = __builtin_amdgcn_mfma_f32_16x16x32_f16(ub1, b0, acc10, 0, 0, 0);
        acc11 = __builtin_amdgcn_mfma_f32_16x16x32_f16(ub1, b1, acc11, 0, 0, 0);
    }
    #pragma unroll
    for (int r = 0; r < 4; r++){
        int ea0 = eb + q * 4 + r;
        if (ea0 < NE){
            int d = dst[ea0];
            atomicAdd(&aggr[(size_t)d * 32 + m],      acc00[r]);
            atomicAdd(&aggr[(size_t)d * 32 + 16 + m], acc01[r]);
        }
        int ea1 = eb + 16 + q * 4 + r;
        if (ea1 < NE){
            int d = dst[ea1];
            atomicAdd(&aggr[(size_t)d * 32 + m],      acc10[r]);
            atomicAdd(&aggr[(size_t)d * 32 + 16 + m], acc11[r]);
        }
    }
}

// =====================================================================
// k_gru R17: MFMA GRU. Wave = 16 nodes. Weights = 14 fp16 B-fragment
// tiles (gateB, L2-hot, lane-linear). Activations split fp16 hi+lo
// (2 MFMAs each -> ~fp32 accuracy; only W rounding remains).
// Layouts (round-3-verified): A row=l&15, k=(l>>4)*8+i; B col=l&15;
// D col=l&15 (B-col), row=(l>>4)*4+r (A-row).
// mv redistributed D->A layout via padded per-wave LDS bounce.
// =====================================================================
__global__ __launch_bounds__(256) void k_gru(
    float* __restrict__ aggr, const float* __restrict__ deg,
    float* __restrict__ h, halfT* __restrict__ hH,
    const halfT* __restrict__ gateB,
    const float* __restrict__ gbih, const float* __restrict__ gbhh,
    const float* __restrict__ cb)
{
    __shared__ float hbuf[4][16][33];
    __shared__ float mbuf[4][16][33];
    int tid = threadIdx.x;
    int w = tid >> 6, l = tid & 63;
    int m16 = l & 15, q = l >> 4;
    int nb = blockIdx.x * 64 + w * 16;      // wave's base node
    // h A-frag (row = node = m16), cache fp32 row-slice in hbuf, split hi/lo
    float hv[8];
    const float* hp = h + (size_t)(nb + m16) * 32 + q * 8;
    *(float4*)&hv[0] = *(const float4*)(hp);
    *(float4*)&hv[4] = *(const float4*)(hp + 4);
    half8 h_hi, h_lo;
    #pragma unroll
    for (int i = 0; i < 8; i++){
        halfT hi = (halfT)hv[i];
        h_hi[i] = hi;
        h_lo[i] = (halfT)(hv[i] - (float)hi);
        hbuf[w][m16][q * 8 + i] = hv[i];
    }
    // stage 1: mv = h @ rootW (2 c-tiles)
    f32x4 macc0 = {0,0,0,0}, macc1 = {0,0,0,0};
    {
        half8 B0 = *(const half8*)(gateB + ((size_t)0 * 64 + l) * 8);
        half8 B1 = *(const half8*)(gateB + ((size_t)1 * 64 + l) * 8);
        macc0 = __builtin_amdgcn_mfma_f32_16x16x32_f16(h_hi, B0, macc0, 0, 0, 0);
        macc0 = __builtin_amdgcn_mfma_f32_16x16x32_f16(h_lo, B0, macc0, 0, 0, 0);
        macc1 = __builtin_amdgcn_mfma_f32_16x16x32_f16(h_hi, B1, macc1, 0, 0, 0);
        macc1 = __builtin_amdgcn_mfma_f32_16x16x32_f16(h_lo, B1, macc1, 0, 0, 0);
    }
    // mv += aggr/deg + cb, relu; re-zero aggr; write mbuf (D layout)
    {
        float cb0 = cb[m16], cb1 = cb[16 + m16];
        #pragma unroll
        for (int r = 0; r < 4; r++){
            int nr = q * 4 + r;
            int node = nb + nr;
            float invd = 1.f / fmaxf(deg[node], 1.f);
            size_t a0 = (size_t)node * 32 + m16;
            size_t a1 = a0 + 16;
            float av0 = aggr[a0]; aggr[a0] = 0.f;
            float av1 = aggr[a1]; aggr[a1] = 0.f;
            float mv0 = fmaxf(macc0[r] + av0 * invd + cb0, 0.f);
            float mv1 = fmaxf(macc1[r] + av1 * invd + cb1, 0.f);
            mbuf[w][nr][m16]      = mv0;
            mbuf[w][nr][16 + m16] = mv1;
        }
    }
    __syncthreads();
    // m A-frag (row = node = m16), split hi/lo
    half8 m_hi, m_lo;
    #pragma unroll
    for (int i = 0; i < 8; i++){
        float mval = mbuf[w][m16][q * 8 + i];
        halfT hi = (halfT)mval;
        m_hi[i] = hi;
        m_lo[i] = (halfT)(mval - (float)hi);
    }
    // stage 2: gx = m @ Wih (tiles 2-7), gh = h @ Whh (tiles 8-13)
    f32x4 gx[6], gh[6];
    #pragma unroll
    for (int t = 0; t < 6; t++){ gx[t] = (f32x4){0,0,0,0}; gh[t] = (f32x4){0,0,0,0}; }
    #pragma unroll
    for (int t = 0; t < 6; t++){
        half8 Bx = *(const half8*)(gateB + ((size_t)(2 + t) * 64 + l) * 8);
        half8 Bh = *(const half8*)(gateB + ((size_t)(8 + t) * 64 + l) * 8);
        gx[t] = __builtin_amdgcn_mfma_f32_16x16x32_f16(m_hi, Bx, gx[t], 0, 0, 0);
        gx[t] = __builtin_amdgcn_mfma_f32_16x16x32_f16(m_lo, Bx, gx[t], 0, 0, 0);
        gh[t] = __builtin_amdgcn_mfma_f32_16x16x32_f16(h_hi, Bh, gh[t], 0, 0, 0);
        gh[t] = __builtin_amdgcn_mfma_f32_16x16x32_f16(h_lo, Bh, gh[t], 0, 0, 0);
    }
    // elementwise GRU + store (lane: nodes q*4+r, channels m16 and 16+m16)
    #pragma unroll
    for (int t = 0; t < 2; t++){
        int c = t * 16 + m16;
        float bxr = gbih[c],      bhr = gbhh[c];
        float bxz = gbih[32 + c], bhz = gbhh[32 + c];
        float bxn = gbih[64 + c], bhn = gbhh[64 + c];
        #pragma unroll
        for (int r = 0; r < 4; r++){
            int nr = q * 4 + r;
            int node = nb + nr;
            float rr = sigf(gx[t][r] + bxr + gh[t][r] + bhr);
            float zz = sigf(gx[2 + t][r] + bxz + gh[2 + t][r] + bhz);
            float nn = tanh_f(gx[4 + t][r] + bxn + rr * (gh[4 + t][r] + bhn));
            float hq = hbuf[w][nr][c];
            float hnew = (1.f - zz) * nn + zz * hq;
            h[(size_t)node * 32 + c]  = hnew;
            hH[(size_t)node * 32 + c] = (halfT)hnew;
        }
    }
}

// =====================================================================
// k_s2s: LDS-cached Set2Set + final MLP.  [unchanged]
// =====================================================================
__global__ __launch_bounds__(64) void k_s2s(
    const float* __restrict__ h, const int* __restrict__ starts,
    const float* __restrict__ lWihT, const float* __restrict__ lWhhT,
    const float* __restrict__ lbih, const float* __restrict__ lbhh,
    const float* __restrict__ lin1T, const float* __restrict__ lin1_b,
    const float* __restrict__ lin2W, const float* __restrict__ lin2b,
    float* __restrict__ e_buf, float* __restrict__ out)
{
    __shared__ float hl[MAXN * 33];
    __shared__ float al[MAXN];
    __shared__ float hsl[32];
    int g = blockIdx.x, l = threadIdx.x;
    int s0 = starts[g], s1 = starts[g + 1];
    int n = s1 - s0;
    int c = l & 31, grp = l >> 5;
    int nl = (n < MAXN) ? n : MAXN;
    for (int idx = l; idx < nl * 32; idx += 64)
        hl[(idx >> 5) * 33 + (idx & 31)] = h[(size_t)s0 * 32 + idx];
    __syncthreads();
    float qs = 0.f, hsv = 0.f, csv = 0.f;
    for (int t = 0; t < 3; t++){
        float a1 = lbih[l] + lbhh[l];
        float a2 = lbih[l + 64] + lbhh[l + 64];
        #pragma unroll 8
        for (int k = 0; k < 64; k++){
            float qk = __shfl(qs, k);
            a1 += qk * lWihT[k * 128 + l];
            a2 += qk * lWihT[k * 128 + 64 + l];
        }
        #pragma unroll 8
        for (int k = 0; k < 32; k++){
            float hk = __shfl(qs, k);
            a1 += hk * lWhhT[k * 128 + l];
            a2 += hk * lWhhT[k * 128 + 64 + l];
        }
        float gate1 = sigf(a1);
        float gate2 = (l < 32) ? tanhf(a2) : sigf(a2);
        float fv = __shfl(gate1, c + 32);
        float ov = __shfl(gate2, c + 32);
        if (l < 32){
            csv = fv * csv + gate1 * gate2;
            hsv = ov * tanhf(csv);
            hsl[l] = hsv;
        }
        __syncthreads();
        float lmax = -3.4e38f;
        for (int i = l; i < n; i += 64){
            const float* hr = (i < MAXN) ? &hl[i * 33] : &h[(size_t)(s0 + i) * 32];
            float p = 0.f;
            #pragma unroll
            for (int c2 = 0; c2 < 32; c2++) p += hr[c2] * hsl[c2];
            if (i < MAXN) al[i] = p; else e_buf[s0 + i] = p;
            lmax = fmaxf(lmax, p);
        }
        #pragma unroll
        for (int o = 1; o < 64; o <<= 1) lmax = fmaxf(lmax, __shfl_xor(lmax, o));
        float lsum = 0.f;
        for (int i = l; i < n; i += 64){
            float e = (i < MAXN) ? al[i] : e_buf[s0 + i];
            float a = expf(e - lmax);
            if (i < MAXN) al[i] = a; else e_buf[s0 + i] = a;
            lsum += a;
        }
        #pragma unroll
        for (int o = 1; o < 64; o <<= 1) lsum += __shfl_xor(lsum, o);
        float inv = (lsum > 0.f) ? 1.f / lsum : 0.f;
        __syncthreads();
        float acc = 0.f;
        for (int i = grp; i < n; i += 2){
            float a = (i < MAXN) ? al[i] : e_buf[s0 + i];
            const float* hr = (i < MAXN) ? &hl[i * 33] : &h[(size_t)(s0 + i) * 32];
            acc += a * hr[c];
        }
        acc *= inv;
        acc += __shfl_xor(acc, 32);
        qs = (l < 32) ? hsv : acc;
        __syncthreads();
    }
    float s = lin1_b[c];
    #pragma unroll 8
    for (int k = 0; k < 64; k++){
        float qk = __shfl(qs, k);
        s += qk * lin1T[k * 32 + c];
    }
    float pp = (l < 32) ? fmaxf(s, 0.f) * lin2W[c] : 0.f;
    pp += __shfl_xor(pp, 1);  pp += __shfl_xor(pp, 2);
    pp += __shfl_xor(pp, 4);  pp += __shfl_xor(pp, 8);
    pp += __shfl_xor(pp, 16); pp += __shfl_xor(pp, 32);
    if (l == 0) out[g] = pp + lin2b[0];
}

extern "C" void kernel_launch(void* const* d_in, const int* in_sizes, int n_in,
                              void* d_out, int out_size, void* d_ws, size_t ws_size,
                              hipStream_t stream){
    (void)in_sizes; (void)n_in; (void)out_size;
    const float* x        = (const float*)d_in[0];
    const float* ea       = (const float*)d_in[1];
    const int*   ei       = (const int*)d_in[2];
    const int*   batch    = (const int*)d_in[3];
    const float* lin0_W   = (const float*)d_in[4];
    const float* lin0_b   = (const float*)d_in[5];
    const float* mlp_W1   = (const float*)d_in[6];
    const float* mlp_b1   = (const float*)d_in[7];
    const float* mlp_W2   = (const float*)d_in[8];
    const float* mlp_b2   = (const float*)d_in[9];
    const float* root_W   = (const float*)d_in[10];
    const float* conv_b   = (const float*)d_in[11];
    const float* gWih     = (const float*)d_in[12];
    const float* gWhh     = (const float*)d_in[13];
    const float* gbih     = (const float*)d_in[14];
    const float* gbhh     = (const float*)d_in[15];
    const float* lWih     = (const float*)d_in[16];
    const float* lWhh     = (const float*)d_in[17];
    const float* lbih     = (const float*)d_in[18];
    const float* lbhh     = (const float*)d_in[19];
    const float* lin1_W   = (const float*)d_in[20];
    const float* lin1_b   = (const float*)d_in[21];
    const float* lin2_W   = (const float*)d_in[22];
    const float* lin2_b   = (const float*)d_in[23];
    const int* src = ei;
    const int* dst = ei + NE;
    float* out = (float*)d_out;

    char* w = (char*)d_ws;
    size_t off = 0;
    auto alloc = [&](size_t bytes) -> void* {
        void* p = w + off;
        off = (off + bytes + 255) & ~(size_t)255;
        return p;
    };
    float* deg    = (float*)alloc((size_t)NN * 4);            // contiguous with aggr
    float* aggr   = (float*)alloc((size_t)NN * 32 * 4);
    float* h      = (float*)alloc((size_t)NN * 32 * 4);
    halfT* hH     = (halfT*)alloc((size_t)NN * 32 * 2);
    halfT* ehF    = (halfT*)alloc((size_t)NEP * 128 * 2);
    halfT* BfF    = (halfT*)alloc((size_t)129 * 2 * 64 * 8 * 2);
    int*   starts = (int*)alloc((size_t)(NB + 1) * 4);
    halfT* gateB  = (halfT*)alloc((size_t)14 * 64 * 8 * 2);
    float* lWihT  = (float*)alloc((size_t)8192 * 4);
    float* lWhhT  = (float*)alloc((size_t)4096 * 4);
    float* lin1T  = (float*)alloc((size_t)2048 * 4);
    float* e_buf  = (float*)alloc((size_t)NN * 4);
    if (ws_size < off) return;   // cannot run

    hipMemsetAsync(deg, 0, (size_t)NN * 4 + (size_t)NN * 32 * 4, stream);

    k_setup<<<8526, 256, 0, stream>>>(x, lin0_W, lin0_b, ea, mlp_W1, mlp_b1,
        mlp_W2, mlp_b2, dst, batch, root_W, gWih, gWhh, lWih, lWhh, lin1_W,
        h, hH, ehF, BfF, deg, gateB, lWihT, lWhhT, lin1T, starts);

    for (int t = 0; t < 3; t++){
        k_msg4<<<NEP / 256, 512, 0, stream>>>(ehF, BfF, hH, src, dst, aggr);
        k_gru<<<NN / 64, 256, 0, stream>>>(aggr, deg, h, hH, gateB,
                                           gbih, gbhh, conv_b);
    }
    k_s2s<<<NB, 64, 0, stream>>>(h, starts, lWihT, lWhhT, lbih, lbhh,
                                 lin1T, lin1_b, lin2_W, lin2_b, e_buf, out);
}

// Round 19
// 183.415 us; speedup vs baseline: 1.7155x; 1.0073x over previous
//
#include <hip/hip_runtime.h>
#include <hip/hip_bf16.h>
#include <cstdint>

#define NN 40000
#define NE 100000
#define NEP 100096           // 32-aligned edge count
#define NB 1024
#define MAXN 192             // per-graph LDS node cache capacity

typedef _Float16 halfT;
typedef _Float16 half8 __attribute__((ext_vector_type(8)));
typedef float f32x4 __attribute__((ext_vector_type(4)));

static __device__ __forceinline__ float sigf(float x){ return 1.f/(1.f + __expf(-x)); }
static __device__ __forceinline__ float tanh_f(float x){ float e = __expf(2.f * x); return 1.f - 2.f/(e + 1.f); }

// =====================================================================
// k_setup: one kernel, 7 block-ranges.  [unchanged from R17]
// =====================================================================
__global__ __launch_bounds__(256) void k_setup(
    const float* __restrict__ x, const float* __restrict__ lin0_W, const float* __restrict__ lin0_b,
    const float* __restrict__ ea, const float* __restrict__ W1, const float* __restrict__ b1,
    const float* __restrict__ W2, const float* __restrict__ b2,
    const int* __restrict__ dstA, const int* __restrict__ batch,
    const float* __restrict__ rootW,
    const float* __restrict__ gWih, const float* __restrict__ gWhh,
    const float* __restrict__ lWih, const float* __restrict__ lWhh, const float* __restrict__ lin1_W,
    float* __restrict__ h, halfT* __restrict__ hH, halfT* __restrict__ ehF, halfT* __restrict__ BfF,
    float* __restrict__ deg, halfT* __restrict__ gateB,
    float* __restrict__ lWihT, float* __restrict__ lWhhT, float* __restrict__ lin1T,
    int* __restrict__ starts)
{
    int b = blockIdx.x, tid = threadIdx.x;
    if (b < 1250){
        __shared__ float sW[32 * 30];
        __shared__ float sB[32];
        for (int idx = tid; idx < 960; idx += 256) sW[idx] = lin0_W[idx];
        if (tid < 32) sB[tid] = lin0_b[tid];
        __syncthreads();
        int t8 = b * 256 + tid;             // [0, NN*8)
        int i = t8 >> 3, q4 = t8 & 7;       // node, channel-quad
        const float* xr = x + (size_t)i * 30;
        float xv[30];
        #pragma unroll
        for (int f = 0; f < 30; f++) xv[f] = xr[f];
        float r[4];
        #pragma unroll
        for (int cc = 0; cc < 4; cc++){
            int c = q4 * 4 + cc;
            const float* wr = &sW[c * 30];
            float s = sB[c];
            #pragma unroll
            for (int f = 0; f < 30; f++) s += xv[f] * wr[f];
            r[cc] = fmaxf(s, 0.f);
        }
        *(float4*)(h + (size_t)i * 32 + q4 * 4) = *(float4*)r;
        halfT rh[4];
        #pragma unroll
        for (int cc = 0; cc < 4; cc++) rh[cc] = (halfT)r[cc];
        *(uint2*)(hH + (size_t)i * 32 + q4 * 4) = *(uint2*)rh;
    } else if (b < 7506){
        __shared__ float sW1[128 * 11];
        __shared__ float sb1[128];
        for (int idx = tid; idx < 1408; idx += 256) sW1[idx] = W1[idx];
        if (tid < 128) sb1[tid] = b1[tid];
        __syncthreads();
        int t8 = (b - 1250) * 256 + tid;    // [0, NEP*16)
        int ch = t8 & 63;
        int s4 = (t8 >> 6) & 3;
        int g16 = t8 >> 8;
        int m = ch & 15, q = ch >> 4;       // lane-linear content
        int e = g16 * 16 + m;
        int kb = 32 * s4 + q * 8;
        halfT v[8];
        if (e < NE){
            const float* xr = ea + (size_t)e * 11;
            float xv[11];
            #pragma unroll
            for (int f = 0; f < 11; f++) xv[f] = xr[f];
            #pragma unroll
            for (int i8 = 0; i8 < 8; i8++){
                int k = kb + i8;
                const float* wr = &sW1[k * 11];
                float s = sb1[k];
                #pragma unroll
                for (int f = 0; f < 11; f++) s += xv[f] * wr[f];
                v[i8] = (halfT)fmaxf(s, 0.f);
            }
        } else {
            #pragma unroll
            for (int i8 = 0; i8 < 8; i8++) v[i8] = (halfT)0.f;
        }
        *(half8*)(ehF + (size_t)t8 * 8) = *(half8*)v;
    } else if (b < 8022){
        int gid = (b - 7506) * 256 + tid;   // 129*2*64*8 = 132096
        int i8 = gid & 7;
        int ch = (gid >> 3) & 63;
        int nt = (gid >> 9) & 1;
        int ks = gid >> 10;
        int m = ch & 15, q = ch >> 4;       // lane-linear content
        int o = nt * 16 + m;
        float v;
        if (ks < 128){
            int c = ks >> 2;
            int k = 32 * (ks & 3) + q * 8 + i8;
            v = W2[(size_t)(c * 32 + o) * 128 + k];
        } else {
            int c = q * 8 + i8;
            v = b2[c * 32 + o];
        }
        BfF[gid] = (halfT)v;
    } else if (b < 8413){
        int e = (b - 8022) * 256 + tid;
        if (e < NE) atomicAdd(&deg[dstA[e]], 1.f);
    } else if (b < 8493){
        int t = (b - 8413) * 256 + tid;     // 20480 (s2s weight transposes)
        if (t < 8192){ int k = t >> 7, j = t & 127; lWihT[t] = lWih[(size_t)j * 64 + k]; }
        else if (t < 12288){ int t2 = t - 8192; int k = t2 >> 7, j = t2 & 127; lWhhT[t2] = lWhh[(size_t)j * 32 + k]; }
        else if (t < 14336){ int t2 = t - 12288; int k = t2 >> 5, c = t2 & 31; lin1T[t2] = lin1_W[(size_t)c * 64 + k]; }
    } else if (b < 8498){
        int g = (b - 8493) * 256 + tid;
        if (g > NB) return;
        int lo = 0, hi = NN;
        while (lo < hi){
            int mid = (lo + hi) >> 1;
            if (batch[mid] < g) lo = mid + 1; else hi = mid;
        }
        starts[g] = lo;
    } else {
        int t = (b - 8498) * 256 + tid;     // 14*64*8 = 7168 gateB entries
        if (t >= 7168) return;
        int tile = t >> 9;
        int l = (t >> 3) & 63;
        int i = t & 7;
        int m = l & 15, q = l >> 4;
        int k = q * 8 + i;
        float v;
        if (tile < 2){
            int c = tile * 16 + m;
            v = rootW[(size_t)k * 32 + c];
        } else if (tile < 8){
            int j = (tile - 2) * 16 + m;
            v = gWih[(size_t)j * 32 + k];
        } else {
            int j = (tile - 8) * 16 + m;
            v = gWhh[(size_t)j * 32 + k];
        }
        gateB[t] = (halfT)v;
    }
}

// =====================================================================
// k_msg4 R18: K-group widened 8->16 ks (32KB double-buffered LDS, 64KB
// total) -> 8 barriers per dispatch instead of 16. Occupancy unchanged
// (grid 391 blocks is the cap, 64KB still allows 2 blocks/CU).
// Everything else identical to R17.
// =====================================================================
__global__ __launch_bounds__(512, 4) void k_msg4(
    const halfT* __restrict__ ehF, const halfT* __restrict__ BfF,
    const halfT* __restrict__ hH,
    const int* __restrict__ src, const int* __restrict__ dst,
    float* __restrict__ aggr)
{
    __shared__ halfT sB[2][16384];       // 2 x 32KB (16 ks per group)
    int tid = threadIdx.x;               // 0..511
    int l = tid & 63;
    int wid = blockIdx.x * 8 + (tid >> 6);
    int m = l & 15, q = l >> 4;
    int eb = wid * 32;
    // stage group 0 -> LDS (512 threads x 4 half8 = 32KB)
    half8 pre[4];
    #pragma unroll
    for (int p = 0; p < 4; p++)
        pre[p] = *(const half8*)(BfF + (size_t)(p * 512 + tid) * 8);
    #pragma unroll
    for (int p = 0; p < 4; p++)
        *(half8*)(&sB[0][(p * 512 + tid) * 8]) = pre[p];
    // per-wave operand fragments (latency overlaps staging)
    half8 u0[4], u1[4], ub0, ub1;
    {
        int e0 = eb + m;      int se0 = (e0 < NE) ? src[e0] : 0;
        int e1 = eb + 16 + m; int se1 = (e1 < NE) ? src[e1] : 0;
        const halfT* p0 = hH + (size_t)se0 * 32;
        const halfT* p1 = hH + (size_t)se1 * 32;
        #pragma unroll
        for (int j = 0; j < 4; j++){
            u0[j] = *(const half8*)(p0 + j * 8);
            u1[j] = *(const half8*)(p1 + j * 8);
        }
        ub0 = *(const half8*)(p0 + q * 8);
        ub1 = *(const half8*)(p1 + q * 8);
    }
    half8 eh0[4], eh1[4];
    {
        int g0 = eb >> 4;
        #pragma unroll
        for (int s = 0; s < 4; s++){
            eh0[s] = *(const half8*)(ehF + ((size_t)(g0 * 4 + s) * 64 + l) * 8);
            eh1[s] = *(const half8*)(ehF + ((size_t)((g0 + 1) * 4 + s) * 64 + l) * 8);
        }
    }
    __syncthreads();
    // prefetch group 1 into regs
    #pragma unroll
    for (int p = 0; p < 4; p++)
        pre[p] = *(const half8*)(BfF + (size_t)16384 + (size_t)(p * 512 + tid) * 8);
    f32x4 acc00 = {0,0,0,0}, acc01 = {0,0,0,0}, acc10 = {0,0,0,0}, acc11 = {0,0,0,0};
    #pragma unroll
    for (int g = 0; g < 8; g++){
        const int cur = g & 1;
        #pragma unroll
        for (int j = 0; j < 16; j++){
            const int ks = g * 16 + j;
            half8 b0 = *(const half8*)(&sB[cur][(j * 2 + 0) * 512 + l * 8]);
            half8 b1 = *(const half8*)(&sB[cur][(j * 2 + 1) * 512 + l * 8]);
            const int c = ks >> 2, s = ks & 3;
            halfT uc0 = u0[c >> 3][c & 7];
            halfT uc1 = u1[c >> 3][c & 7];
            half8 a0 = eh0[s] * uc0;
            half8 a1 = eh1[s] * uc1;
            acc00 = __builtin_amdgcn_mfma_f32_16x16x32_f16(a0, b0, acc00, 0, 0, 0);
            acc01 = __builtin_amdgcn_mfma_f32_16x16x32_f16(a0, b1, acc01, 0, 0, 0);
            acc10 = __builtin_amdgcn_mfma_f32_16x16x32_f16(a1, b0, acc10, 0, 0, 0);
            acc11 = __builtin_amdgcn_mfma_f32_16x16x32_f16(a1, b1, acc11, 0, 0, 0);
        }
        if (g + 1 < 8){
            #pragma unroll
            for (int p = 0; p < 4; p++)
                *(half8*)(&sB[cur ^ 1][(p * 512 + tid) * 8]) = pre[p];
            if (g + 2 < 8){
                #pragma unroll
                for (int p = 0; p < 4; p++)
                    pre[p] = *(const half8*)(BfF + (size_t)(g + 2) * 16384 + (size_t)(p * 512 + tid) * 8);
            }
        }
        __syncthreads();
    }
    {   // bias K-tile (ks = 128) straight from global (L2-hot, one shot)
        half8 b0 = *(const half8*)(BfF + (size_t)256 * 512 + l * 8);
        half8 b1 = *(const half8*)(BfF + (size_t)257 * 512 + l * 8);
        acc00 = __builtin_amdgcn_mfma_f32_16x16x32_f16(ub0, b0, acc00, 0, 0, 0);
        acc01 = __builtin_amdgcn_mfma_f32_16x16x32_f16(ub0, b1, acc01, 0, 0, 0);
        acc10 = __builtin_amdgcn_mfma_f32_16x16x32_f16(ub1, b0, acc10, 0, 0, 0);
        acc11 = __builtin_amdgcn_mfma_f32_16x16x32_f16(ub1, b1, acc11, 0, 0, 0);
    }
    // scatter: lane holds msg[e = eb+G*16+q*4+r][o = nt*16+m]
    #pragma unroll
    for (int r = 0; r < 4; r++){
        int ea0 = eb + q * 4 + r;
        if (ea0 < NE){
            int d = dst[ea0];
            atomicAdd(&aggr[(size_t)d * 32 + m],      acc00[r]);
            atomicAdd(&aggr[(size_t)d * 32 + 16 + m], acc01[r]);
        }
        int ea1 = eb + 16 + q * 4 + r;
        if (ea1 < NE){
            int d = dst[ea1];
            atomicAdd(&aggr[(size_t)d * 32 + m],      acc10[r]);
            atomicAdd(&aggr[(size_t)d * 32 + 16 + m], acc11[r]);
        }
    }
}

// =====================================================================
// k_gru: MFMA GRU (R17).  [unchanged]
// =====================================================================
__global__ __launch_bounds__(256) void k_gru(
    float* __restrict__ aggr, const float* __restrict__ deg,
    float* __restrict__ h, halfT* __restrict__ hH,
    const halfT* __restrict__ gateB,
    const float* __restrict__ gbih, const float* __restrict__ gbhh,
    const float* __restrict__ cb)
{
    __shared__ float hbuf[4][16][33];
    __shared__ float mbuf[4][16][33];
    int tid = threadIdx.x;
    int w = tid >> 6, l = tid & 63;
    int m16 = l & 15, q = l >> 4;
    int nb = blockIdx.x * 64 + w * 16;      // wave's base node
    float hv[8];
    const float* hp = h + (size_t)(nb + m16) * 32 + q * 8;
    *(float4*)&hv[0] = *(const float4*)(hp);
    *(float4*)&hv[4] = *(const float4*)(hp + 4);
    half8 h_hi, h_lo;
    #pragma unroll
    for (int i = 0; i < 8; i++){
        halfT hi = (halfT)hv[i];
        h_hi[i] = hi;
        h_lo[i] = (halfT)(hv[i] - (float)hi);
        hbuf[w][m16][q * 8 + i] = hv[i];
    }
    f32x4 macc0 = {0,0,0,0}, macc1 = {0,0,0,0};
    {
        half8 B0 = *(const half8*)(gateB + ((size_t)0 * 64 + l) * 8);
        half8 B1 = *(const half8*)(gateB + ((size_t)1 * 64 + l) * 8);
        macc0 = __builtin_amdgcn_mfma_f32_16x16x32_f16(h_hi, B0, macc0, 0, 0, 0);
        macc0 = __builtin_amdgcn_mfma_f32_16x16x32_f16(h_lo, B0, macc0, 0, 0, 0);
        macc1 = __builtin_amdgcn_mfma_f32_16x16x32_f16(h_hi, B1, macc1, 0, 0, 0);
        macc1 = __builtin_amdgcn_mfma_f32_16x16x32_f16(h_lo, B1, macc1, 0, 0, 0);
    }
    {
        float cb0 = cb[m16], cb1 = cb[16 + m16];
        #pragma unroll
        for (int r = 0; r < 4; r++){
            int nr = q * 4 + r;
            int node = nb + nr;
            float invd = 1.f / fmaxf(deg[node], 1.f);
            size_t a0 = (size_t)node * 32 + m16;
            size_t a1 = a0 + 16;
            float av0 = aggr[a0]; aggr[a0] = 0.f;
            float av1 = aggr[a1]; aggr[a1] = 0.f;
            float mv0 = fmaxf(macc0[r] + av0 * invd + cb0, 0.f);
            float mv1 = fmaxf(macc1[r] + av1 * invd + cb1, 0.f);
            mbuf[w][nr][m16]      = mv0;
            mbuf[w][nr][16 + m16] = mv1;
        }
    }
    __syncthreads();
    half8 m_hi, m_lo;
    #pragma unroll
    for (int i = 0; i < 8; i++){
        float mval = mbuf[w][m16][q * 8 + i];
        halfT hi = (halfT)mval;
        m_hi[i] = hi;
        m_lo[i] = (halfT)(mval - (float)hi);
    }
    f32x4 gx[6], gh[6];
    #pragma unroll
    for (int t = 0; t < 6; t++){ gx[t] = (f32x4){0,0,0,0}; gh[t] = (f32x4){0,0,0,0}; }
    #pragma unroll
    for (int t = 0; t < 6; t++){
        half8 Bx = *(const half8*)(gateB + ((size_t)(2 + t) * 64 + l) * 8);
        half8 Bh = *(const half8*)(gateB + ((size_t)(8 + t) * 64 + l) * 8);
        gx[t] = __builtin_amdgcn_mfma_f32_16x16x32_f16(m_hi, Bx, gx[t], 0, 0, 0);
        gx[t] = __builtin_amdgcn_mfma_f32_16x16x32_f16(m_lo, Bx, gx[t], 0, 0, 0);
        gh[t] = __builtin_amdgcn_mfma_f32_16x16x32_f16(h_hi, Bh, gh[t], 0, 0, 0);
        gh[t] = __builtin_amdgcn_mfma_f32_16x16x32_f16(h_lo, Bh, gh[t], 0, 0, 0);
    }
    #pragma unroll
    for (int t = 0; t < 2; t++){
        int c = t * 16 + m16;
        float bxr = gbih[c],      bhr = gbhh[c];
        float bxz = gbih[32 + c], bhz = gbhh[32 + c];
        float bxn = gbih[64 + c], bhn = gbhh[64 + c];
        #pragma unroll
        for (int r = 0; r < 4; r++){
            int nr = q * 4 + r;
            int node = nb + nr;
            float rr = sigf(gx[t][r] + bxr + gh[t][r] + bhr);
            float zz = sigf(gx[2 + t][r] + bxz + gh[2 + t][r] + bhz);
            float nn = tanh_f(gx[4 + t][r] + bxn + rr * (gh[4 + t][r] + bhn));
            float hq = hbuf[w][nr][c];
            float hnew = (1.f - zz) * nn + zz * hq;
            h[(size_t)node * 32 + c]  = hnew;
            hH[(size_t)node * 32 + c] = (halfT)hnew;
        }
    }
}

// =====================================================================
// k_s2s: LDS-cached Set2Set + final MLP.  [unchanged]
// =====================================================================
__global__ __launch_bounds__(64) void k_s2s(
    const float* __restrict__ h, const int* __restrict__ starts,
    const float* __restrict__ lWihT, const float* __restrict__ lWhhT,
    const float* __restrict__ lbih, const float* __restrict__ lbhh,
    const float* __restrict__ lin1T, const float* __restrict__ lin1_b,
    const float* __restrict__ lin2W, const float* __restrict__ lin2b,
    float* __restrict__ e_buf, float* __restrict__ out)
{
    __shared__ float hl[MAXN * 33];
    __shared__ float al[MAXN];
    __shared__ float hsl[32];
    int g = blockIdx.x, l = threadIdx.x;
    int s0 = starts[g], s1 = starts[g + 1];
    int n = s1 - s0;
    int c = l & 31, grp = l >> 5;
    int nl = (n < MAXN) ? n : MAXN;
    for (int idx = l; idx < nl * 32; idx += 64)
        hl[(idx >> 5) * 33 + (idx & 31)] = h[(size_t)s0 * 32 + idx];
    __syncthreads();
    float qs = 0.f, hsv = 0.f, csv = 0.f;
    for (int t = 0; t < 3; t++){
        float a1 = lbih[l] + lbhh[l];
        float a2 = lbih[l + 64] + lbhh[l + 64];
        #pragma unroll 8
        for (int k = 0; k < 64; k++){
            float qk = __shfl(qs, k);
            a1 += qk * lWihT[k * 128 + l];
            a2 += qk * lWihT[k * 128 + 64 + l];
        }
        #pragma unroll 8
        for (int k = 0; k < 32; k++){
            float hk = __shfl(qs, k);
            a1 += hk * lWhhT[k * 128 + l];
            a2 += hk * lWhhT[k * 128 + 64 + l];
        }
        float gate1 = sigf(a1);
        float gate2 = (l < 32) ? tanhf(a2) : sigf(a2);
        float fv = __shfl(gate1, c + 32);
        float ov = __shfl(gate2, c + 32);
        if (l < 32){
            csv = fv * csv + gate1 * gate2;
            hsv = ov * tanhf(csv);
            hsl[l] = hsv;
        }
        __syncthreads();
        float lmax = -3.4e38f;
        for (int i = l; i < n; i += 64){
            const float* hr = (i < MAXN) ? &hl[i * 33] : &h[(size_t)(s0 + i) * 32];
            float p = 0.f;
            #pragma unroll
            for (int c2 = 0; c2 < 32; c2++) p += hr[c2] * hsl[c2];
            if (i < MAXN) al[i] = p; else e_buf[s0 + i] = p;
            lmax = fmaxf(lmax, p);
        }
        #pragma unroll
        for (int o = 1; o < 64; o <<= 1) lmax = fmaxf(lmax, __shfl_xor(lmax, o));
        float lsum = 0.f;
        for (int i = l; i < n; i += 64){
            float e = (i < MAXN) ? al[i] : e_buf[s0 + i];
            float a = expf(e - lmax);
            if (i < MAXN) al[i] = a; else e_buf[s0 + i] = a;
            lsum += a;
        }
        #pragma unroll
        for (int o = 1; o < 64; o <<= 1) lsum += __shfl_xor(lsum, o);
        float inv = (lsum > 0.f) ? 1.f / lsum : 0.f;
        __syncthreads();
        float acc = 0.f;
        for (int i = grp; i < n; i += 2){
            float a = (i < MAXN) ? al[i] : e_buf[s0 + i];
            const float* hr = (i < MAXN) ? &hl[i * 33] : &h[(size_t)(s0 + i) * 32];
            acc += a * hr[c];
        }
        acc *= inv;
        acc += __shfl_xor(acc, 32);
        qs = (l < 32) ? hsv : acc;
        __syncthreads();
    }
    float s = lin1_b[c];
    #pragma unroll 8
    for (int k = 0; k < 64; k++){
        float qk = __shfl(qs, k);
        s += qk * lin1T[k * 32 + c];
    }
    float pp = (l < 32) ? fmaxf(s, 0.f) * lin2W[c] : 0.f;
    pp += __shfl_xor(pp, 1);  pp += __shfl_xor(pp, 2);
    pp += __shfl_xor(pp, 4);  pp += __shfl_xor(pp, 8);
    pp += __shfl_xor(pp, 16); pp += __shfl_xor(pp, 32);
    if (l == 0) out[g] = pp + lin2b[0];
}

extern "C" void kernel_launch(void* const* d_in, const int* in_sizes, int n_in,
                              void* d_out, int out_size, void* d_ws, size_t ws_size,
                              hipStream_t stream){
    (void)in_sizes; (void)n_in; (void)out_size;
    const float* x        = (const float*)d_in[0];
    const float* ea       = (const float*)d_in[1];
    const int*   ei       = (const int*)d_in[2];
    const int*   batch    = (const int*)d_in[3];
    const float* lin0_W   = (const float*)d_in[4];
    const float* lin0_b   = (const float*)d_in[5];
    const float* mlp_W1   = (const float*)d_in[6];
    const float* mlp_b1   = (const float*)d_in[7];
    const float* mlp_W2   = (const float*)d_in[8];
    const float* mlp_b2   = (const float*)d_in[9];
    const float* root_W   = (const float*)d_in[10];
    const float* conv_b   = (const float*)d_in[11];
    const float* gWih     = (const float*)d_in[12];
    const float* gWhh     = (const float*)d_in[13];
    const float* gbih     = (const float*)d_in[14];
    const float* gbhh     = (const float*)d_in[15];
    const float* lWih     = (const float*)d_in[16];
    const float* lWhh     = (const float*)d_in[17];
    const float* lbih     = (const float*)d_in[18];
    const float* lbhh     = (const float*)d_in[19];
    const float* lin1_W   = (const float*)d_in[20];
    const float* lin1_b   = (const float*)d_in[21];
    const float* lin2_W   = (const float*)d_in[22];
    const float* lin2_b   = (const float*)d_in[23];
    const int* src = ei;
    const int* dst = ei + NE;
    float* out = (float*)d_out;

    char* w = (char*)d_ws;
    size_t off = 0;
    auto alloc = [&](size_t bytes) -> void* {
        void* p = w + off;
        off = (off + bytes + 255) & ~(size_t)255;
        return p;
    };
    float* deg    = (float*)alloc((size_t)NN * 4);            // contiguous with aggr
    float* aggr   = (float*)alloc((size_t)NN * 32 * 4);
    float* h      = (float*)alloc((size_t)NN * 32 * 4);
    halfT* hH     = (halfT*)alloc((size_t)NN * 32 * 2);
    halfT* ehF    = (halfT*)alloc((size_t)NEP * 128 * 2);
    halfT* BfF    = (halfT*)alloc((size_t)129 * 2 * 64 * 8 * 2);
    int*   starts = (int*)alloc((size_t)(NB + 1) * 4);
    halfT* gateB  = (halfT*)alloc((size_t)14 * 64 * 8 * 2);
    float* lWihT  = (float*)alloc((size_t)8192 * 4);
    float* lWhhT  = (float*)alloc((size_t)4096 * 4);
    float* lin1T  = (float*)alloc((size_t)2048 * 4);
    float* e_buf  = (float*)alloc((size_t)NN * 4);
    if (ws_size < off) return;   // cannot run

    hipMemsetAsync(deg, 0, (size_t)NN * 4 + (size_t)NN * 32 * 4, stream);

    k_setup<<<8526, 256, 0, stream>>>(x, lin0_W, lin0_b, ea, mlp_W1, mlp_b1,
        mlp_W2, mlp_b2, dst, batch, root_W, gWih, gWhh, lWih, lWhh, lin1_W,
        h, hH, ehF, BfF, deg, gateB, lWihT, lWhhT, lin1T, starts);

    for (int t = 0; t < 3; t++){
        k_msg4<<<NEP / 256, 512, 0, stream>>>(ehF, BfF, hH, src, dst, aggr);
        k_gru<<<NN / 64, 256, 0, stream>>>(aggr, deg, h, hH, gateB,
                                           gbih, gbhh, conv_b);
    }
    k_s2s<<<NB, 64, 0, stream>>>(h, starts, lWihT, lWhhT, lbih, lbhh,
                                 lin1T, lin1_b, lin2_W, lin2_b, e_buf, out);
}